// Round 17
// baseline (314.439 us; speedup 1.0000x reference)
//
#include <hip/hip_runtime.h>

#define HID 2048
#define SEQ 2048
#define HD 128
#define QKN 6144      // 3*HID

typedef float f32x4 __attribute__((ext_vector_type(4)));
typedef short s16x8 __attribute__((ext_vector_type(8)));
typedef __bf16 bf16x8 __attribute__((ext_vector_type(8)));

static __device__ __forceinline__ unsigned short f2bf(float x) {
    unsigned u = __float_as_uint(x);
    u = u + 0x7FFFu + ((u >> 16) & 1u);   // RNE
    return (unsigned short)(u >> 16);
}
static __device__ __forceinline__ float bf2f(unsigned short h) {
    return __uint_as_float(((unsigned)h) << 16);
}
static __device__ __forceinline__ bf16x8 as_bf(s16x8 v) {
    union { s16x8 s; bf16x8 b; } u; u.s = v; return u.b;
}
static __device__ __forceinline__ bf16x8 ld_bf8(const unsigned short* p) {
    return as_bf(*(const s16x8*)p);
}
// async global->LDS, 16B/lane; LDS dest = wave-uniform base + lane*16 (m104)
static __device__ __forceinline__ void gload_lds16(const void* g, void* l) {
    __builtin_amdgcn_global_load_lds(
        (const __attribute__((address_space(1))) void*)g,
        (__attribute__((address_space(3))) void*)l,
        16, 0, 0);
}

__global__ __launch_bounds__(256) void fill_f32(
    float* __restrict__ out, float v, int n)
{
    int i = blockIdx.x * 256 + threadIdx.x;
    if (i < n) out[i] = v;
}

// ---------------- fp32 -> bf16 convert (8 elems/thread) ----------------
__global__ __launch_bounds__(256) void convert_f32_bf16(
    const float* __restrict__ in, unsigned short* __restrict__ out)
{
    long i = ((long)blockIdx.x * 256 + threadIdx.x) * 8;
    f32x4 a = *(const f32x4*)&in[i];
    f32x4 b = *(const f32x4*)&in[i + 4];
    s16x8 o;
#pragma unroll
    for (int e = 0; e < 4; ++e) {
        o[e]     = (short)f2bf(a[e]);
        o[e + 4] = (short)f2bf(b[e]);
    }
    *(s16x8*)&out[i] = o;
}

// ---------------- W[k][n] fp32 -> Wt[n][k] bf16 (tiled transpose) ----------------
__global__ __launch_bounds__(256) void transpose_w(
    const float* __restrict__ W, unsigned short* __restrict__ Wt)
{
    __shared__ float t[32][33];
    int k0 = blockIdx.x * 32, n0 = blockIdx.y * 32;
    int tx = threadIdx.x & 31, ty = threadIdx.x >> 5;
#pragma unroll
    for (int r = ty; r < 32; r += 8)
        t[r][tx] = W[(long)(k0 + r) * HID + n0 + tx];
    __syncthreads();
#pragma unroll
    for (int r = ty; r < 32; r += 8)
        Wt[(long)(n0 + r) * HID + k0 + tx] = f2bf(t[tx][r]);
}

// ======== 256x(NF*64) single-phase GEMM, fat-wave r17: wave-tile 128 x NF*16 ====
// Per K-tile per wave: 2*(NF+8) ds_read_b128, 2*8*NF MFMA (kk-outer keeps VGPR
// under 256 for NF=6). dbuf LDS; counted vmcnt(4+NF); setprio; 2-D XCD chunking.
template<int NF, bool F32OUT>
__global__ __launch_bounds__(512, 2) void gemm_8phase(
    const unsigned short* __restrict__ A,    // [M][K] bf16
    const unsigned short* __restrict__ Bt,   // [N][K] bf16
    const float* __restrict__ bq, const float* __restrict__ bk,
    const float* __restrict__ bv,
    unsigned short* __restrict__ Cb, float* __restrict__ Cf,
    int K, int ldc, int nbn, int sm, int sn, int hasBias)
{
    constexpr int BUFE = 16384 + NF * 4096;      // elems per LDS buffer (A|B)
    __shared__ unsigned short lds[2 * BUFE];
    const int tid = threadIdx.x;
    const int wid = tid >> 6, lane = tid & 63;
    const int l16 = lane & 15, l4 = lane >> 4;
    const int wm = wid >> 2, wn = wid & 3;

    // 2-D XCD chunk decode: 8 chunks of sm x sn tiles
    const int bid = blockIdx.x;
    const int xcd = bid & 7, idx = bid >> 3;
    const int ncn = nbn / sn;                    // chunk-cols
    const int cm = xcd / ncn, cn = xcd % ncn;
    const int lm = idx / sn,  ln = idx % sn;
    const long bm = (long)(cm * sm + lm) * 256;
    const long bn = (long)(cn * sn + ln) * (NF * 64);

    const int NT = K >> 6;
    const long strideB = (long)K * 2;            // bytes per global row
    const int srow = tid >> 3;                   // 0..63 row within 64-row chunk
    const int scb  = ((tid & 7) * 16) ^ ((srow & 7) << 4);   // pre-swizzled src byte

    auto stageA = [&](int t, int c) {            // c in 0..3
        unsigned short* base = &lds[(t & 1) * BUFE];
        const int row = c * 64 + srow;
        const char* src = (const char*)A + (bm + row) * strideB + (long)t * 128 + scb;
        gload_lds16(src, base + (c * 64 + wid * 8) * 64);
    };
    auto stageB = [&](int t, int c) {            // c in 0..NF-1
        unsigned short* base = &lds[(t & 1) * BUFE + 16384];
        const int row = c * 64 + srow;
        const char* src = (const char*)Bt + (bn + row) * strideB + (long)t * 128 + scb;
        gload_lds16(src, base + (c * 64 + wid * 8) * 64);
    };

    f32x4 acc[8][NF];
#pragma unroll
    for (int i = 0; i < 8; ++i)
#pragma unroll
        for (int j = 0; j < NF; ++j) acc[i][j] = f32x4{0.f, 0.f, 0.f, 0.f};

    // compute one K-tile: kk-outer so only one kk's fragments are live at once
    // (acc 4*8*NF + bfr 4*NF + af 16 VGPR peak). Per-acc kk order ascending ->
    // bit-identical accumulation vs kk-inner.
    auto compute = [&](const unsigned short* Ab, const unsigned short* Bb) {
#pragma unroll
        for (int kk = 0; kk < 2; ++kk) {
            bf16x8 bfr[NF];
#pragma unroll
            for (int j = 0; j < NF; ++j) {
                const int row = wn * (NF * 16) + j * 16 + l16;
                const char* rb = (const char*)Bb + row * 128;
                bfr[j] = as_bf(*(const s16x8*)(rb + ((kk * 64 + l4 * 16) ^ ((l16 & 7) << 4))));
            }
#pragma unroll
            for (int half = 0; half < 2; ++half) {
                bf16x8 af[4];
#pragma unroll
                for (int i = 0; i < 4; ++i) {
                    const int row = wm * 128 + (half * 4 + i) * 16 + l16;
                    const char* rb = (const char*)Ab + row * 128;
                    af[i] = as_bf(*(const s16x8*)(rb + ((kk * 64 + l4 * 16) ^ ((l16 & 7) << 4))));
                }
                __builtin_amdgcn_s_setprio(1);
#pragma unroll
                for (int i = 0; i < 4; ++i)
#pragma unroll
                    for (int j = 0; j < NF; ++j)
                        acc[half * 4 + i][j] = __builtin_amdgcn_mfma_f32_16x16x32_bf16(
                            af[i], bfr[j], acc[half * 4 + i][j], 0, 0, 0);
                __builtin_amdgcn_s_setprio(0);
            }
        }
    };

    // prologue: stage tile 0 fully (4+NF loads/thread)
#pragma unroll
    for (int c = 0; c < 4; ++c) stageA(0, c);
#pragma unroll
    for (int c = 0; c < NF; ++c) stageB(0, c);

    for (int t = 0; t < NT - 1; ++t) {
        const unsigned short* Ab = &lds[(t & 1) * BUFE];
        const unsigned short* Bb = Ab + 16384;
#pragma unroll
        for (int c = 0; c < 4; ++c) stageA(t + 1, c);
#pragma unroll
        for (int c = 0; c < NF; ++c) stageB(t + 1, c);
        __builtin_amdgcn_sched_barrier(0);
        // counted wait: tile t's (4+NF) loads done, tile t+1's in flight
        if constexpr (NF == 6)      asm volatile("s_waitcnt vmcnt(10)" ::: "memory");
        else if constexpr (NF == 3) asm volatile("s_waitcnt vmcnt(7)" ::: "memory");
        else                        asm volatile("s_waitcnt vmcnt(6)" ::: "memory");
        __builtin_amdgcn_s_barrier();
        __builtin_amdgcn_sched_barrier(0);                 // no ds_read above validity
        compute(Ab, Bb);
        __builtin_amdgcn_s_barrier();   // all reads of buf done before t+2 staging
    }
    {
        const unsigned short* Ab = &lds[((NT - 1) & 1) * BUFE];
        const unsigned short* Bb = Ab + 16384;
        asm volatile("s_waitcnt vmcnt(0)" ::: "memory");
        __builtin_amdgcn_s_barrier();
        __builtin_amdgcn_sched_barrier(0);
        compute(Ab, Bb);
    }

    // epilogue: C/D map col=l16, row=l4*4+r (m89)
#pragma unroll
    for (int nf = 0; nf < NF; ++nf) {
        const long n = bn + wn * (NF * 16) + nf * 16 + l16;
        float bvv = 0.f;
        if (hasBias)
            bvv = (n < HID) ? bq[n] : ((n < 2 * HID) ? bk[n - HID] : bv[n - 2 * HID]);
#pragma unroll
        for (int mf = 0; mf < 8; ++mf) {
#pragma unroll
            for (int r = 0; r < 4; ++r) {
                const long m = bm + wm * 128 + mf * 16 + l4 * 4 + r;
                float v = acc[mf][nf][r] + bvv;
                if (F32OUT) Cf[m * (long)ldc + n] = v;
                else        Cb[m * (long)ldc + n] = f2bf(v);
            }
        }
    }
}

// ---------------- RoPE in place on Q,K halves; folds 1/sqrt(128) into Q ------
__global__ __launch_bounds__(256) void rope_kernel(unsigned short* __restrict__ qkv)
{
    int t = blockIdx.x * 256 + threadIdx.x;   // 1,048,576 total
    int j8 = t & 7;
    int h  = (t >> 3) & 15;
    int qk = (t >> 7) & 1;                    // 0 = Q, 1 = K
    int row = t >> 8;                         // 0..4095
    int s = row & (SEQ - 1);
    unsigned short* p = &qkv[(long)row * QKN + qk * HID + h * HD + j8 * 8];
    s16x8 lo = *(const s16x8*)p;
    s16x8 hi = *(const s16x8*)(p + 64);
    float qscale = qk ? 1.0f : 0.08838834764831845f;
    s16x8 olo, ohi;
#pragma unroll
    for (int e = 0; e < 8; ++e) {
        int j = j8 * 8 + e;                   // 0..63
        float inv = exp2f(-(float)j * 0.20762050593046f);  // 10000^(-j/64)
        float sn, cs;
        sincosf((float)s * inv, &sn, &cs);
        float x1 = bf2f((unsigned short)lo[e]);
        float x2 = bf2f((unsigned short)hi[e]);
        olo[e] = (short)f2bf((x1 * cs - x2 * sn) * qscale);
        ohi[e] = (short)f2bf((x2 * cs + x1 * sn) * qscale);
    }
    *(s16x8*)p = olo;
    *(s16x8*)(p + 64) = ohi;
}

// ---------------- V[b,s,h,d] -> VT[b,h,d,s] ----------------
__global__ __launch_bounds__(256) void v_transpose(
    const unsigned short* __restrict__ qkv, unsigned short* __restrict__ vt)
{
    __shared__ unsigned short t[32][33];
    int bh = blockIdx.z;
    int b = bh >> 4, h = bh & 15;
    int s0 = blockIdx.x * 32, d0 = blockIdx.y * 32;
    int tx = threadIdx.x & 31, ty = threadIdx.x >> 5;
#pragma unroll
    for (int r = ty; r < 32; r += 8)
        t[r][tx] = qkv[(long)(b * SEQ + s0 + r) * QKN + 2 * HID + h * HD + d0 + tx];
    __syncthreads();
#pragma unroll
    for (int r = ty; r < 32; r += 8)
        vt[((long)bh * HD + d0 + r) * SEQ + s0 + tx] = t[tx][r];
}

// -------- MFMA flash attention (r14 best-known): 8 waves / QBLK=128, T2
// swizzles, dbuf staging, defer-max, swapped-QK^T in-register softmax.
// XCD-chunked: each XCD owns 4 heads x 16 q-tiles (K/V L2-resident).
__global__ __launch_bounds__(512) void attn_kernel(
    const unsigned short* __restrict__ qkv,
    const unsigned short* __restrict__ vt,
    unsigned short* __restrict__ attnout)
{
    __shared__ unsigned short Ks[2][64 * 128];   // [kv][d], byte ^= (kv&7)<<4
    __shared__ unsigned short Vs[2][128 * 64];   // [d][kv], byte ^= (d&7)<<4

    const int tid = threadIdx.x, wid = tid >> 6, lane = tid & 63;
    const int l16 = lane & 15, l4 = lane >> 4;
    const int bid = blockIdx.x;                  // 0..511
    const int xcd = bid & 7, idx = bid >> 3;     // idx 0..63
    const int bh = xcd * 4 + (idx >> 4);         // 4 heads per XCD
    const int qt = idx & 15;                     // 16 q-tiles (QBLK=128)
    const int b = bh >> 4, h = bh & 15;
    const long rowbase = (long)b * SEQ;

    const unsigned short* Kg = &qkv[rowbase * QKN + HID + h * HD];  // + s*QKN
    const unsigned short* Vg = &vt[(long)bh * HD * SEQ];            // + d*SEQ

    // 16 K chunks + 16 V chunks over 8 waves -> 2+2 per wave
    auto stage = [&](int buf, int kv0) {
#pragma unroll
        for (int i = 0; i < 2; ++i) {
            int c = wid * 2 + i;
            int kr = c * 4 + l4;
            int kcb = (l16 * 16) ^ ((kr & 7) << 4);
            gload_lds16((const char*)(Kg + (long)(kv0 + kr) * QKN) + kcb, &Ks[buf][c * 512]);
            int vr = c * 8 + (lane >> 3);
            int vcb = ((lane & 7) * 16) ^ ((vr & 7) << 4);
            gload_lds16((const char*)(Vg + (long)vr * SEQ + kv0) + vcb, &Vs[buf][c * 512]);
        }
    };

    bf16x8 qf[4];
    {
        const long qrow = rowbase + qt * 128 + wid * 16 + l16;
        const unsigned short* qp = &qkv[qrow * QKN + h * HD];
#pragma unroll
        for (int kc = 0; kc < 4; ++kc) qf[kc] = ld_bf8(qp + kc * 32 + l4 * 8);
    }

    f32x4 o[8];
#pragma unroll
    for (int nb = 0; nb < 8; ++nb) o[nb] = f32x4{0.f, 0.f, 0.f, 0.f};
    float mrun = -3.0e38f, lrun = 0.f;       // per-lane scalars (q = l16)

    const int srcA = ((l4 & 1) * 2) * 16 + l16;   // lane of l4_s = 2(l4&1)
    const int srcB = srcA + 16;                   // lane of l4_s = 2(l4&1)+1
    const bool sel = (l4 >> 1) != 0;              // nf_s = 2kc + (l4>>1)

    stage(0, 0);
    __syncthreads();

    for (int t = 0; t < SEQ / 64; ++t) {
        const int cur = t & 1;
        if (t < SEQ / 64 - 1) stage(cur ^ 1, (t + 1) * 64);
        __builtin_amdgcn_sched_barrier(0);   // pin: issue next-tile stage first

        const unsigned short* Kc = &Ks[cur][0];
        const unsigned short* Vc = &Vs[cur][0];

        // S^T = K Q^T: A = kf (rows=kv), B = qf (cols=q)
        f32x4 sc[4];
#pragma unroll
        for (int nf = 0; nf < 4; ++nf) sc[nf] = f32x4{0.f, 0.f, 0.f, 0.f};
#pragma unroll
        for (int kc = 0; kc < 4; ++kc) {
#pragma unroll
            for (int nf = 0; nf < 4; ++nf) {
                int row = nf * 16 + l16;
                int cb = (kc * 64 + l4 * 16) ^ ((row & 7) << 4);
                bf16x8 kf = as_bf(*(const s16x8*)((const char*)Kc + row * 256 + cb));
                sc[nf] = __builtin_amdgcn_mfma_f32_16x16x32_bf16(kf, qf[kc], sc[nf], 0, 0, 0);
            }
        }

        // per-lane max over 16 values, then combine 4 l4-copies
        float tmax = sc[0][0];
#pragma unroll
        for (int nf = 0; nf < 4; ++nf)
#pragma unroll
            for (int r = 0; r < 4; ++r) tmax = fmaxf(tmax, sc[nf][r]);
        tmax = fmaxf(tmax, __shfl_xor(tmax, 16, 64));
        tmax = fmaxf(tmax, __shfl_xor(tmax, 32, 64));

        // defer-max (T13): skip rescale when max growth <= 8 (wave-uniform)
        if (!__all(tmax - mrun <= 8.0f)) {
            float mn = fmaxf(mrun, tmax);
            float sc_ = __expf(mrun - mn);
            mrun = mn;
            lrun *= sc_;
            float s_[4];
#pragma unroll
            for (int r = 0; r < 4; ++r) s_[r] = __shfl(sc_, l4 * 4 + r, 64);
#pragma unroll
            for (int nb = 0; nb < 8; ++nb)
#pragma unroll
                for (int r = 0; r < 4; ++r) o[nb][r] *= s_[r];
        }

        // P = exp(S - m); pack to bf16 pairs; sum
        unsigned pk[4][2];
        float sum = 0.f;
#pragma unroll
        for (int nf = 0; nf < 4; ++nf) {
            float p0 = __expf(sc[nf][0] - mrun);
            float p1 = __expf(sc[nf][1] - mrun);
            float p2 = __expf(sc[nf][2] - mrun);
            float p3 = __expf(sc[nf][3] - mrun);
            sum += (p0 + p1) + (p2 + p3);
            union { __bf16 b[2]; unsigned u; } w0, w1;
            w0.b[0] = (__bf16)p0; w0.b[1] = (__bf16)p1;
            w1.b[0] = (__bf16)p2; w1.b[1] = (__bf16)p3;
            pk[nf][0] = w0.u; pk[nf][1] = w1.u;
        }
        sum += __shfl_xor(sum, 16, 64);
        sum += __shfl_xor(sum, 32, 64);
        lrun += sum;

        // redistribute P into PV A-fragments (4-lane group exchange)
        union { unsigned u[4]; bf16x8 v; } pa0, pa1;
#pragma unroll
        for (int w = 0; w < 2; ++w) {
            unsigned a0 = __shfl(pk[0][w], srcA, 64);
            unsigned a1 = __shfl(pk[1][w], srcA, 64);
            unsigned b0 = __shfl(pk[0][w], srcB, 64);
            unsigned b1 = __shfl(pk[1][w], srcB, 64);
            pa0.u[w]     = sel ? a1 : a0;
            pa0.u[2 + w] = sel ? b1 : b0;
            unsigned c0 = __shfl(pk[2][w], srcA, 64);
            unsigned c1 = __shfl(pk[3][w], srcA, 64);
            unsigned d0 = __shfl(pk[2][w], srcB, 64);
            unsigned d1 = __shfl(pk[3][w], srcB, 64);
            pa1.u[w]     = sel ? c1 : c0;
            pa1.u[2 + w] = sel ? d1 : d0;
        }

        // O += P V   (A = pa (q rows), B = V^T [d][kv] swizzled)
#pragma unroll
        for (int kc = 0; kc < 2; ++kc) {
            bf16x8 pav = kc ? pa1.v : pa0.v;
#pragma unroll
            for (int nb = 0; nb < 8; ++nb) {
                int vrow = nb * 16 + l16;
                int vcb = (kc * 64 + l4 * 16) ^ ((vrow & 7) << 4);
                bf16x8 vb = as_bf(*(const s16x8*)((const char*)Vc + vrow * 128 + vcb));
                o[nb] = __builtin_amdgcn_mfma_f32_16x16x32_bf16(pav, vb, o[nb], 0, 0, 0);
            }
        }
        __syncthreads();   // implicit vmcnt(0): next-tile stage (issued pre-compute) done
    }

    // stats live at q=l16 lanes; o rows are q=l4*4+r -> hop via 4 shuffles
    float linv = 1.f / lrun;
    float li[4];
#pragma unroll
    for (int r = 0; r < 4; ++r) li[r] = __shfl(linv, l4 * 4 + r, 64);
#pragma unroll
    for (int r = 0; r < 4; ++r) {
        long m = rowbase + qt * 128 + wid * 16 + l4 * 4 + r;
#pragma unroll
        for (int nb = 0; nb < 8; ++nb)
            attnout[m * HID + h * HD + nb * 16 + l16] = f2bf(o[nb][r] * li[r]);
    }
}

// ---------------- launch ----------------
extern "C" void kernel_launch(void* const* d_in, const int* in_sizes, int n_in,
                              void* d_out, int out_size, void* d_ws, size_t ws_size,
                              hipStream_t stream)
{
    const float* hs = (const float*)d_in[0];
    const float* Wq = (const float*)d_in[1];
    const float* bq = (const float*)d_in[2];
    const float* Wk = (const float*)d_in[3];
    const float* bk = (const float*)d_in[4];
    const float* Wv = (const float*)d_in[5];
    const float* bv = (const float*)d_in[6];
    const float* Wo = (const float*)d_in[7];
    float* out = (float*)d_out;   // fp32 output (confirmed round 5)

    bool shapes_ok =
        (n_in == 8) && (out_size == 8388608) &&
        in_sizes[0] == 8388608 && in_sizes[1] == 4194304 && in_sizes[2] == 2048 &&
        in_sizes[3] == 4194304 && in_sizes[4] == 2048 && in_sizes[5] == 4194304 &&
        in_sizes[6] == 2048 && in_sizes[7] == 4194304;
    if (!shapes_ok || ws_size < 117440512ull) {
        fill_f32<<<32768, 256, 0, stream>>>(out, shapes_ok ? 1000.f : 0.f, out_size);
        return;
    }

    char* ws = (char*)d_ws;
    unsigned short* hsB     = (unsigned short*)(ws);              // [4096][2048] bf16
    unsigned short* qkvB    = (unsigned short*)(ws + 16777216);   // [4096][6144] bf16
    unsigned short* wqkvT   = (unsigned short*)(ws + 67108864);   // [6144][2048] bf16
    unsigned short* vtB     = (unsigned short*)(ws + 92274688);   // [32][128][2048] bf16
    unsigned short* woT     = (unsigned short*)(ws + 109051904);  // [2048][2048] bf16
    unsigned short* attnout = hsB;   // hsB dead after QKV GEMM

    convert_f32_bf16<<<4096, 256, 0, stream>>>(hs, hsB);
    dim3 tg(64, 64);
    transpose_w<<<tg, 256, 0, stream>>>(Wq, wqkvT);
    transpose_w<<<tg, 256, 0, stream>>>(Wk, wqkvT + 2048 * 2048);
    transpose_w<<<tg, 256, 0, stream>>>(Wv, wqkvT + 2 * 2048 * 2048);
    transpose_w<<<tg, 256, 0, stream>>>(Wo, woT);

    // QKV fat-wave: 256x384 tiles -> 16 x 16 = 256 blocks = exactly 1 round;
    // LDS 2x80 KiB = 160 KiB; XCD chunks 8m x 4n (nbn=16 -> ncn=4, 2x4 chunk grid)
    gemm_8phase<6, false><<<dim3(256), 512, 0, stream>>>(
        hsB, wqkvT, bq, bk, bv, qkvB, nullptr, 2048, QKN, 16, 8, 4, 1);
    rope_kernel<<<4096, 256, 0, stream>>>(qkvB);
    v_transpose<<<dim3(64, 4, 32), 256, 0, stream>>>(qkvB, vtB);
    // attn: QBLK=128, 8 waves, 512 blocks, XCD-chunked (4 heads x 16 qt per XCD)
    attn_kernel<<<dim3(512), 512, 0, stream>>>(qkvB, vtB, attnout);
    // out-proj: 256x128 tiles, 16x16 grid, XCD chunks 4x8, fp32 out
    gemm_8phase<2, true><<<dim3(256), 512, 0, stream>>>(
        attnout, woT, nullptr, nullptr, nullptr, nullptr, out, 2048, HID, 16, 4, 8, 0);
}

// Round 18
// 300.810 us; speedup vs baseline: 1.0453x; 1.0453x over previous
//
#include <hip/hip_runtime.h>

#define HID 2048
#define SEQ 2048
#define HD 128
#define QKN 6144      // 3*HID

typedef float f32x4 __attribute__((ext_vector_type(4)));
typedef short s16x8 __attribute__((ext_vector_type(8)));
typedef __bf16 bf16x8 __attribute__((ext_vector_type(8)));

static __device__ __forceinline__ unsigned short f2bf(float x) {
    unsigned u = __float_as_uint(x);
    u = u + 0x7FFFu + ((u >> 16) & 1u);   // RNE
    return (unsigned short)(u >> 16);
}
static __device__ __forceinline__ float bf2f(unsigned short h) {
    return __uint_as_float(((unsigned)h) << 16);
}
static __device__ __forceinline__ bf16x8 as_bf(s16x8 v) {
    union { s16x8 s; bf16x8 b; } u; u.s = v; return u.b;
}
static __device__ __forceinline__ bf16x8 ld_bf8(const unsigned short* p) {
    return as_bf(*(const s16x8*)p);
}
// async global->LDS, 16B/lane; LDS dest = wave-uniform base + lane*16 (m104)
static __device__ __forceinline__ void gload_lds16(const void* g, void* l) {
    __builtin_amdgcn_global_load_lds(
        (const __attribute__((address_space(1))) void*)g,
        (__attribute__((address_space(3))) void*)l,
        16, 0, 0);
}

__global__ __launch_bounds__(256) void fill_f32(
    float* __restrict__ out, float v, int n)
{
    int i = blockIdx.x * 256 + threadIdx.x;
    if (i < n) out[i] = v;
}

// ---------------- fp32 -> bf16 convert (8 elems/thread) ----------------
__global__ __launch_bounds__(256) void convert_f32_bf16(
    const float* __restrict__ in, unsigned short* __restrict__ out)
{
    long i = ((long)blockIdx.x * 256 + threadIdx.x) * 8;
    f32x4 a = *(const f32x4*)&in[i];
    f32x4 b = *(const f32x4*)&in[i + 4];
    s16x8 o;
#pragma unroll
    for (int e = 0; e < 4; ++e) {
        o[e]     = (short)f2bf(a[e]);
        o[e + 4] = (short)f2bf(b[e]);
    }
    *(s16x8*)&out[i] = o;
}

// ---------------- W[k][n] fp32 -> Wt[n][k] bf16 (tiled transpose) ----------------
__global__ __launch_bounds__(256) void transpose_w(
    const float* __restrict__ W, unsigned short* __restrict__ Wt)
{
    __shared__ float t[32][33];
    int k0 = blockIdx.x * 32, n0 = blockIdx.y * 32;
    int tx = threadIdx.x & 31, ty = threadIdx.x >> 5;
#pragma unroll
    for (int r = ty; r < 32; r += 8)
        t[r][tx] = W[(long)(k0 + r) * HID + n0 + tx];
    __syncthreads();
#pragma unroll
    for (int r = ty; r < 32; r += 8)
        Wt[(long)(n0 + r) * HID + k0 + tx] = f2bf(t[tx][r]);
}

// ======== 256x(NF*64) single-phase GEMM, fat-wave: wave-tile 128 x NF*16 ====
// dbuf LDS; counted vmcnt(4+NF); setprio; 2-D XCD chunking.
// r18: epilogue loops reordered (row-outer, nf-inner) so same-row stores are
// consecutive -> TCC write-combining (WRITE_SIZE was 1.76x ideal).
template<int NF, bool F32OUT>
__global__ __launch_bounds__(512, 2) void gemm_8phase(
    const unsigned short* __restrict__ A,    // [M][K] bf16
    const unsigned short* __restrict__ Bt,   // [N][K] bf16
    const float* __restrict__ bq, const float* __restrict__ bk,
    const float* __restrict__ bv,
    unsigned short* __restrict__ Cb, float* __restrict__ Cf,
    int K, int ldc, int nbn, int sm, int sn, int hasBias)
{
    constexpr int BUFE = 16384 + NF * 4096;      // elems per LDS buffer (A|B)
    __shared__ unsigned short lds[2 * BUFE];
    const int tid = threadIdx.x;
    const int wid = tid >> 6, lane = tid & 63;
    const int l16 = lane & 15, l4 = lane >> 4;
    const int wm = wid >> 2, wn = wid & 3;

    // 2-D XCD chunk decode: 8 chunks of sm x sn tiles
    const int bid = blockIdx.x;
    const int xcd = bid & 7, idx = bid >> 3;
    const int ncn = nbn / sn;                    // chunk-cols
    const int cm = xcd / ncn, cn = xcd % ncn;
    const int lm = idx / sn,  ln = idx % sn;
    const long bm = (long)(cm * sm + lm) * 256;
    const long bn = (long)(cn * sn + ln) * (NF * 64);

    const int NT = K >> 6;
    const long strideB = (long)K * 2;            // bytes per global row
    const int srow = tid >> 3;                   // 0..63 row within 64-row chunk
    const int scb  = ((tid & 7) * 16) ^ ((srow & 7) << 4);   // pre-swizzled src byte

    auto stageA = [&](int t, int c) {            // c in 0..3
        unsigned short* base = &lds[(t & 1) * BUFE];
        const int row = c * 64 + srow;
        const char* src = (const char*)A + (bm + row) * strideB + (long)t * 128 + scb;
        gload_lds16(src, base + (c * 64 + wid * 8) * 64);
    };
    auto stageB = [&](int t, int c) {            // c in 0..NF-1
        unsigned short* base = &lds[(t & 1) * BUFE + 16384];
        const int row = c * 64 + srow;
        const char* src = (const char*)Bt + (bn + row) * strideB + (long)t * 128 + scb;
        gload_lds16(src, base + (c * 64 + wid * 8) * 64);
    };

    f32x4 acc[8][NF];
#pragma unroll
    for (int i = 0; i < 8; ++i)
#pragma unroll
        for (int j = 0; j < NF; ++j) acc[i][j] = f32x4{0.f, 0.f, 0.f, 0.f};

    // compute one K-tile: kk-outer so only one kk's fragments are live at once
    auto compute = [&](const unsigned short* Ab, const unsigned short* Bb) {
#pragma unroll
        for (int kk = 0; kk < 2; ++kk) {
            bf16x8 bfr[NF];
#pragma unroll
            for (int j = 0; j < NF; ++j) {
                const int row = wn * (NF * 16) + j * 16 + l16;
                const char* rb = (const char*)Bb + row * 128;
                bfr[j] = as_bf(*(const s16x8*)(rb + ((kk * 64 + l4 * 16) ^ ((l16 & 7) << 4))));
            }
#pragma unroll
            for (int half = 0; half < 2; ++half) {
                bf16x8 af[4];
#pragma unroll
                for (int i = 0; i < 4; ++i) {
                    const int row = wm * 128 + (half * 4 + i) * 16 + l16;
                    const char* rb = (const char*)Ab + row * 128;
                    af[i] = as_bf(*(const s16x8*)(rb + ((kk * 64 + l4 * 16) ^ ((l16 & 7) << 4))));
                }
                __builtin_amdgcn_s_setprio(1);
#pragma unroll
                for (int i = 0; i < 4; ++i)
#pragma unroll
                    for (int j = 0; j < NF; ++j)
                        acc[half * 4 + i][j] = __builtin_amdgcn_mfma_f32_16x16x32_bf16(
                            af[i], bfr[j], acc[half * 4 + i][j], 0, 0, 0);
                __builtin_amdgcn_s_setprio(0);
            }
        }
    };

    // prologue: stage tile 0 fully (4+NF loads/thread)
#pragma unroll
    for (int c = 0; c < 4; ++c) stageA(0, c);
#pragma unroll
    for (int c = 0; c < NF; ++c) stageB(0, c);

    for (int t = 0; t < NT - 1; ++t) {
        const unsigned short* Ab = &lds[(t & 1) * BUFE];
        const unsigned short* Bb = Ab + 16384;
#pragma unroll
        for (int c = 0; c < 4; ++c) stageA(t + 1, c);
#pragma unroll
        for (int c = 0; c < NF; ++c) stageB(t + 1, c);
        __builtin_amdgcn_sched_barrier(0);
        // counted wait: tile t's (4+NF) loads done, tile t+1's in flight
        if constexpr (NF == 6)      asm volatile("s_waitcnt vmcnt(10)" ::: "memory");
        else if constexpr (NF == 3) asm volatile("s_waitcnt vmcnt(7)" ::: "memory");
        else                        asm volatile("s_waitcnt vmcnt(6)" ::: "memory");
        __builtin_amdgcn_s_barrier();
        __builtin_amdgcn_sched_barrier(0);                 // no ds_read above validity
        compute(Ab, Bb);
        __builtin_amdgcn_s_barrier();   // all reads of buf done before t+2 staging
    }
    {
        const unsigned short* Ab = &lds[((NT - 1) & 1) * BUFE];
        const unsigned short* Bb = Ab + 16384;
        asm volatile("s_waitcnt vmcnt(0)" ::: "memory");
        __builtin_amdgcn_s_barrier();
        __builtin_amdgcn_sched_barrier(0);
        compute(Ab, Bb);
    }

    // epilogue: C/D map col=l16, row=l4*4+r (m89); row-outer / nf-inner so the
    // NF adjacent 32B row-chunks store back-to-back (write combining).
    float bvv[NF];
#pragma unroll
    for (int nf = 0; nf < NF; ++nf) {
        const long n = bn + wn * (NF * 16) + nf * 16 + l16;
        bvv[nf] = 0.f;
        if (hasBias)
            bvv[nf] = (n < HID) ? bq[n] : ((n < 2 * HID) ? bk[n - HID] : bv[n - 2 * HID]);
    }
#pragma unroll
    for (int mf = 0; mf < 8; ++mf) {
#pragma unroll
        for (int r = 0; r < 4; ++r) {
            const long m = bm + wm * 128 + mf * 16 + l4 * 4 + r;
#pragma unroll
            for (int nf = 0; nf < NF; ++nf) {
                const long n = bn + wn * (NF * 16) + nf * 16 + l16;
                float v = acc[mf][nf][r] + bvv[nf];
                if (F32OUT) Cf[m * (long)ldc + n] = v;
                else        Cb[m * (long)ldc + n] = f2bf(v);
            }
        }
    }
}

// ---------------- RoPE in place on Q,K halves ------
// r18: Q scale = 1/sqrt(128) * log2(e) so QK^T lands in log2 domain (softmax
// uses exp2 directly, saving a v_mul per element per tile).
__global__ __launch_bounds__(256) void rope_kernel(unsigned short* __restrict__ qkv)
{
    int t = blockIdx.x * 256 + threadIdx.x;   // 1,048,576 total
    int j8 = t & 7;
    int h  = (t >> 3) & 15;
    int qk = (t >> 7) & 1;                    // 0 = Q, 1 = K
    int row = t >> 8;                         // 0..4095
    int s = row & (SEQ - 1);
    unsigned short* p = &qkv[(long)row * QKN + qk * HID + h * HD + j8 * 8];
    s16x8 lo = *(const s16x8*)p;
    s16x8 hi = *(const s16x8*)(p + 64);
    float qscale = qk ? 1.0f : 0.12751744581845f;   // (1/sqrt(128))*log2(e)
    s16x8 olo, ohi;
#pragma unroll
    for (int e = 0; e < 8; ++e) {
        int j = j8 * 8 + e;                   // 0..63
        float inv = exp2f(-(float)j * 0.20762050593046f);  // 10000^(-j/64)
        float sn, cs;
        sincosf((float)s * inv, &sn, &cs);
        float x1 = bf2f((unsigned short)lo[e]);
        float x2 = bf2f((unsigned short)hi[e]);
        olo[e] = (short)f2bf((x1 * cs - x2 * sn) * qscale);
        ohi[e] = (short)f2bf((x2 * cs + x1 * sn) * qscale);
    }
    *(s16x8*)p = olo;
    *(s16x8*)(p + 64) = ohi;
}

// ---------------- V[b,s,h,d] -> VT[b,h,d,s] ----------------
__global__ __launch_bounds__(256) void v_transpose(
    const unsigned short* __restrict__ qkv, unsigned short* __restrict__ vt)
{
    __shared__ unsigned short t[32][33];
    int bh = blockIdx.z;
    int b = bh >> 4, h = bh & 15;
    int s0 = blockIdx.x * 32, d0 = blockIdx.y * 32;
    int tx = threadIdx.x & 31, ty = threadIdx.x >> 5;
#pragma unroll
    for (int r = ty; r < 32; r += 8)
        t[r][tx] = qkv[(long)(b * SEQ + s0 + r) * QKN + 2 * HID + h * HD + d0 + tx];
    __syncthreads();
#pragma unroll
    for (int r = ty; r < 32; r += 8)
        vt[((long)bh * HD + d0 + r) * SEQ + s0 + tx] = t[tx][r];
}

// -------- MFMA flash attention: 8 waves / QBLK=128, T2 swizzles, dbuf staging,
// defer-max, swapped-QK^T in-register softmax. XCD-chunked.
// r18: log2-domain softmax (exp2f; log2e folded into Q) + max3-tree reduction.
__global__ __launch_bounds__(512) void attn_kernel(
    const unsigned short* __restrict__ qkv,
    const unsigned short* __restrict__ vt,
    unsigned short* __restrict__ attnout)
{
    __shared__ unsigned short Ks[2][64 * 128];   // [kv][d], byte ^= (kv&7)<<4
    __shared__ unsigned short Vs[2][128 * 64];   // [d][kv], byte ^= (d&7)<<4

    const int tid = threadIdx.x, wid = tid >> 6, lane = tid & 63;
    const int l16 = lane & 15, l4 = lane >> 4;
    const int bid = blockIdx.x;                  // 0..511
    const int xcd = bid & 7, idx = bid >> 3;     // idx 0..63
    const int bh = xcd * 4 + (idx >> 4);         // 4 heads per XCD
    const int qt = idx & 15;                     // 16 q-tiles (QBLK=128)
    const int b = bh >> 4, h = bh & 15;
    const long rowbase = (long)b * SEQ;

    const unsigned short* Kg = &qkv[rowbase * QKN + HID + h * HD];  // + s*QKN
    const unsigned short* Vg = &vt[(long)bh * HD * SEQ];            // + d*SEQ

    // 16 K chunks + 16 V chunks over 8 waves -> 2+2 per wave
    auto stage = [&](int buf, int kv0) {
#pragma unroll
        for (int i = 0; i < 2; ++i) {
            int c = wid * 2 + i;
            int kr = c * 4 + l4;
            int kcb = (l16 * 16) ^ ((kr & 7) << 4);
            gload_lds16((const char*)(Kg + (long)(kv0 + kr) * QKN) + kcb, &Ks[buf][c * 512]);
            int vr = c * 8 + (lane >> 3);
            int vcb = ((lane & 7) * 16) ^ ((vr & 7) << 4);
            gload_lds16((const char*)(Vg + (long)vr * SEQ + kv0) + vcb, &Vs[buf][c * 512]);
        }
    };

    bf16x8 qf[4];
    {
        const long qrow = rowbase + qt * 128 + wid * 16 + l16;
        const unsigned short* qp = &qkv[qrow * QKN + h * HD];
#pragma unroll
        for (int kc = 0; kc < 4; ++kc) qf[kc] = ld_bf8(qp + kc * 32 + l4 * 8);
    }

    f32x4 o[8];
#pragma unroll
    for (int nb = 0; nb < 8; ++nb) o[nb] = f32x4{0.f, 0.f, 0.f, 0.f};
    float mrun = -3.0e38f, lrun = 0.f;       // per-lane scalars (q = l16), log2 units

    const int srcA = ((l4 & 1) * 2) * 16 + l16;   // lane of l4_s = 2(l4&1)
    const int srcB = srcA + 16;                   // lane of l4_s = 2(l4&1)+1
    const bool sel = (l4 >> 1) != 0;              // nf_s = 2kc + (l4>>1)

    stage(0, 0);
    __syncthreads();

    for (int t = 0; t < SEQ / 64; ++t) {
        const int cur = t & 1;
        if (t < SEQ / 64 - 1) stage(cur ^ 1, (t + 1) * 64);
        __builtin_amdgcn_sched_barrier(0);   // pin: issue next-tile stage first

        const unsigned short* Kc = &Ks[cur][0];
        const unsigned short* Vc = &Vs[cur][0];

        // S^T = K Q^T (log2 domain): A = kf (rows=kv), B = qf (cols=q)
        f32x4 sc[4];
#pragma unroll
        for (int nf = 0; nf < 4; ++nf) sc[nf] = f32x4{0.f, 0.f, 0.f, 0.f};
#pragma unroll
        for (int kc = 0; kc < 4; ++kc) {
#pragma unroll
            for (int nf = 0; nf < 4; ++nf) {
                int row = nf * 16 + l16;
                int cb = (kc * 64 + l4 * 16) ^ ((row & 7) << 4);
                bf16x8 kf = as_bf(*(const s16x8*)((const char*)Kc + row * 256 + cb));
                sc[nf] = __builtin_amdgcn_mfma_f32_16x16x32_bf16(kf, qf[kc], sc[nf], 0, 0, 0);
            }
        }

        // per-lane max over 16 values via max3 tree, then combine 4 l4-copies
        float m0 = fmaxf(fmaxf(sc[0][0], sc[0][1]), sc[0][2]);
        float m1 = fmaxf(fmaxf(sc[0][3], sc[1][0]), sc[1][1]);
        float m2 = fmaxf(fmaxf(sc[1][2], sc[1][3]), sc[2][0]);
        float m3 = fmaxf(fmaxf(sc[2][1], sc[2][2]), sc[2][3]);
        float m4 = fmaxf(fmaxf(sc[3][0], sc[3][1]), sc[3][2]);
        float tmax = fmaxf(fmaxf(m0, m1), m2);
        tmax = fmaxf(fmaxf(m3, m4), tmax);
        tmax = fmaxf(tmax, sc[3][3]);
        tmax = fmaxf(tmax, __shfl_xor(tmax, 16, 64));
        tmax = fmaxf(tmax, __shfl_xor(tmax, 32, 64));

        // defer-max (T13, log2 units): skip rescale when growth <= 8
        if (!__all(tmax - mrun <= 8.0f)) {
            float mn = fmaxf(mrun, tmax);
            float sc_ = exp2f(mrun - mn);
            mrun = mn;
            lrun *= sc_;
            float s_[4];
#pragma unroll
            for (int r = 0; r < 4; ++r) s_[r] = __shfl(sc_, l4 * 4 + r, 64);
#pragma unroll
            for (int nb = 0; nb < 8; ++nb)
#pragma unroll
                for (int r = 0; r < 4; ++r) o[nb][r] *= s_[r];
        }

        // P = exp2(S - m); pack to bf16 pairs; sum
        unsigned pk[4][2];
        float sum = 0.f;
#pragma unroll
        for (int nf = 0; nf < 4; ++nf) {
            float p0 = exp2f(sc[nf][0] - mrun);
            float p1 = exp2f(sc[nf][1] - mrun);
            float p2 = exp2f(sc[nf][2] - mrun);
            float p3 = exp2f(sc[nf][3] - mrun);
            sum += (p0 + p1) + (p2 + p3);
            union { __bf16 b[2]; unsigned u; } w0, w1;
            w0.b[0] = (__bf16)p0; w0.b[1] = (__bf16)p1;
            w1.b[0] = (__bf16)p2; w1.b[1] = (__bf16)p3;
            pk[nf][0] = w0.u; pk[nf][1] = w1.u;
        }
        sum += __shfl_xor(sum, 16, 64);
        sum += __shfl_xor(sum, 32, 64);
        lrun += sum;

        // redistribute P into PV A-fragments (4-lane group exchange)
        union { unsigned u[4]; bf16x8 v; } pa0, pa1;
#pragma unroll
        for (int w = 0; w < 2; ++w) {
            unsigned a0 = __shfl(pk[0][w], srcA, 64);
            unsigned a1 = __shfl(pk[1][w], srcA, 64);
            unsigned b0 = __shfl(pk[0][w], srcB, 64);
            unsigned b1 = __shfl(pk[1][w], srcB, 64);
            pa0.u[w]     = sel ? a1 : a0;
            pa0.u[2 + w] = sel ? b1 : b0;
            unsigned c0 = __shfl(pk[2][w], srcA, 64);
            unsigned c1 = __shfl(pk[3][w], srcA, 64);
            unsigned d0 = __shfl(pk[2][w], srcB, 64);
            unsigned d1 = __shfl(pk[3][w], srcB, 64);
            pa1.u[w]     = sel ? c1 : c0;
            pa1.u[2 + w] = sel ? d1 : d0;
        }

        // O += P V   (A = pa (q rows), B = V^T [d][kv] swizzled)
#pragma unroll
        for (int kc = 0; kc < 2; ++kc) {
            bf16x8 pav = kc ? pa1.v : pa0.v;
#pragma unroll
            for (int nb = 0; nb < 8; ++nb) {
                int vrow = nb * 16 + l16;
                int vcb = (kc * 64 + l4 * 16) ^ ((vrow & 7) << 4);
                bf16x8 vb = as_bf(*(const s16x8*)((const char*)Vc + vrow * 128 + vcb));
                o[nb] = __builtin_amdgcn_mfma_f32_16x16x32_bf16(pav, vb, o[nb], 0, 0, 0);
            }
        }
        __syncthreads();   // implicit vmcnt(0): next-tile stage (issued pre-compute) done
    }

    // stats live at q=l16 lanes; o rows are q=l4*4+r -> hop via 4 shuffles
    float linv = 1.f / lrun;
    float li[4];
#pragma unroll
    for (int r = 0; r < 4; ++r) li[r] = __shfl(linv, l4 * 4 + r, 64);
#pragma unroll
    for (int r = 0; r < 4; ++r) {
        long m = rowbase + qt * 128 + wid * 16 + l4 * 4 + r;
#pragma unroll
        for (int nb = 0; nb < 8; ++nb)
            attnout[m * HID + h * HD + nb * 16 + l16] = f2bf(o[nb][r] * li[r]);
    }
}

// ---------------- launch ----------------
extern "C" void kernel_launch(void* const* d_in, const int* in_sizes, int n_in,
                              void* d_out, int out_size, void* d_ws, size_t ws_size,
                              hipStream_t stream)
{
    const float* hs = (const float*)d_in[0];
    const float* Wq = (const float*)d_in[1];
    const float* bq = (const float*)d_in[2];
    const float* Wk = (const float*)d_in[3];
    const float* bk = (const float*)d_in[4];
    const float* Wv = (const float*)d_in[5];
    const float* bv = (const float*)d_in[6];
    const float* Wo = (const float*)d_in[7];
    float* out = (float*)d_out;   // fp32 output (confirmed round 5)

    bool shapes_ok =
        (n_in == 8) && (out_size == 8388608) &&
        in_sizes[0] == 8388608 && in_sizes[1] == 4194304 && in_sizes[2] == 2048 &&
        in_sizes[3] == 4194304 && in_sizes[4] == 2048 && in_sizes[5] == 4194304 &&
        in_sizes[6] == 2048 && in_sizes[7] == 4194304;
    if (!shapes_ok || ws_size < 117440512ull) {
        fill_f32<<<32768, 256, 0, stream>>>(out, shapes_ok ? 1000.f : 0.f, out_size);
        return;
    }

    char* ws = (char*)d_ws;
    unsigned short* hsB     = (unsigned short*)(ws);              // [4096][2048] bf16
    unsigned short* qkvB    = (unsigned short*)(ws + 16777216);   // [4096][6144] bf16
    unsigned short* wqkvT   = (unsigned short*)(ws + 67108864);   // [6144][2048] bf16
    unsigned short* vtB     = (unsigned short*)(ws + 92274688);   // [32][128][2048] bf16
    unsigned short* woT     = (unsigned short*)(ws + 109051904);  // [2048][2048] bf16
    unsigned short* attnout = hsB;   // hsB dead after QKV GEMM

    convert_f32_bf16<<<4096, 256, 0, stream>>>(hs, hsB);
    dim3 tg(64, 64);
    transpose_w<<<tg, 256, 0, stream>>>(Wq, wqkvT);
    transpose_w<<<tg, 256, 0, stream>>>(Wk, wqkvT + 2048 * 2048);
    transpose_w<<<tg, 256, 0, stream>>>(Wv, wqkvT + 2 * 2048 * 2048);
    transpose_w<<<tg, 256, 0, stream>>>(Wo, woT);

    // QKV fat-wave: 256x384 tiles -> 16 x 16 = 256 blocks = exactly 1 round
    gemm_8phase<6, false><<<dim3(256), 512, 0, stream>>>(
        hsB, wqkvT, bq, bk, bv, qkvB, nullptr, 2048, QKN, 16, 8, 4, 1);
    rope_kernel<<<4096, 256, 0, stream>>>(qkvB);
    v_transpose<<<dim3(64, 4, 32), 256, 0, stream>>>(qkvB, vtB);
    // attn: QBLK=128, 8 waves, 512 blocks, XCD-chunked (4 heads x 16 qt per XCD)
    attn_kernel<<<dim3(512), 512, 0, stream>>>(qkvB, vtB, attnout);
    // out-proj: 256x128 tiles, 16x16 grid, XCD chunks 4x8, fp32 out
    gemm_8phase<2, true><<<dim3(256), 512, 0, stream>>>(
        attnout, woT, nullptr, nullptr, nullptr, nullptr, out, 2048, HID, 16, 4, 8, 0);
}

// Round 19
// 297.729 us; speedup vs baseline: 1.0561x; 1.0103x over previous
//
#include <hip/hip_runtime.h>

#define HID 2048
#define SEQ 2048
#define HD 128
#define QKN 6144      // 3*HID

typedef float f32x4 __attribute__((ext_vector_type(4)));
typedef short s16x8 __attribute__((ext_vector_type(8)));
typedef __bf16 bf16x8 __attribute__((ext_vector_type(8)));

static __device__ __forceinline__ unsigned short f2bf(float x) {
    unsigned u = __float_as_uint(x);
    u = u + 0x7FFFu + ((u >> 16) & 1u);   // RNE
    return (unsigned short)(u >> 16);
}
static __device__ __forceinline__ float bf2f(unsigned short h) {
    return __uint_as_float(((unsigned)h) << 16);
}
static __device__ __forceinline__ bf16x8 as_bf(s16x8 v) {
    union { s16x8 s; bf16x8 b; } u; u.s = v; return u.b;
}
static __device__ __forceinline__ bf16x8 ld_bf8(const unsigned short* p) {
    return as_bf(*(const s16x8*)p);
}
// async global->LDS, 16B/lane; LDS dest = wave-uniform base + lane*16 (m104)
static __device__ __forceinline__ void gload_lds16(const void* g, void* l) {
    __builtin_amdgcn_global_load_lds(
        (const __attribute__((address_space(1))) void*)g,
        (__attribute__((address_space(3))) void*)l,
        16, 0, 0);
}

__global__ __launch_bounds__(256) void fill_f32(
    float* __restrict__ out, float v, int n)
{
    int i = blockIdx.x * 256 + threadIdx.x;
    if (i < n) out[i] = v;
}

// ---------------- fp32 -> bf16 convert (8 elems/thread) ----------------
__global__ __launch_bounds__(256) void convert_f32_bf16(
    const float* __restrict__ in, unsigned short* __restrict__ out)
{
    long i = ((long)blockIdx.x * 256 + threadIdx.x) * 8;
    f32x4 a = *(const f32x4*)&in[i];
    f32x4 b = *(const f32x4*)&in[i + 4];
    s16x8 o;
#pragma unroll
    for (int e = 0; e < 4; ++e) {
        o[e]     = (short)f2bf(a[e]);
        o[e + 4] = (short)f2bf(b[e]);
    }
    *(s16x8*)&out[i] = o;
}

// ---------------- W[k][n] fp32 -> Wt[n][k] bf16 (tiled transpose) ----------------
__global__ __launch_bounds__(256) void transpose_w(
    const float* __restrict__ W, unsigned short* __restrict__ Wt)
{
    __shared__ float t[32][33];
    int k0 = blockIdx.x * 32, n0 = blockIdx.y * 32;
    int tx = threadIdx.x & 31, ty = threadIdx.x >> 5;
#pragma unroll
    for (int r = ty; r < 32; r += 8)
        t[r][tx] = W[(long)(k0 + r) * HID + n0 + tx];
    __syncthreads();
#pragma unroll
    for (int r = ty; r < 32; r += 8)
        Wt[(long)(n0 + r) * HID + k0 + tx] = f2bf(t[tx][r]);
}

// ======== 256x(NF*64) single-phase GEMM, fat-wave: wave-tile 128 x NF*16 ====
// dbuf LDS; counted vmcnt(4+NF); setprio; 2-D XCD chunking; write-combined
// epilogue. ROPE=true (QKV): rope fused into epilogue via LDS pair-exchange
// (block spans NF/2 whole 128-aligned heads, so pairs (j,j+64) stay in-block).
template<int NF, bool F32OUT, bool ROPE>
__global__ __launch_bounds__(512, 2) void gemm_8phase(
    const unsigned short* __restrict__ A,    // [M][K] bf16
    const unsigned short* __restrict__ Bt,   // [N][K] bf16
    const float* __restrict__ bq, const float* __restrict__ bk,
    const float* __restrict__ bv,
    unsigned short* __restrict__ Cb, float* __restrict__ Cf,
    int K, int ldc, int nbn, int sm, int sn, int hasBias)
{
    constexpr int BUFE = 16384 + NF * 4096;      // elems per LDS buffer (A|B)
    __shared__ unsigned short lds[2 * BUFE];
    const int tid = threadIdx.x;
    const int wid = tid >> 6, lane = tid & 63;
    const int l16 = lane & 15, l4 = lane >> 4;
    const int wm = wid >> 2, wn = wid & 3;

    // 2-D XCD chunk decode: 8 chunks of sm x sn tiles
    const int bid = blockIdx.x;
    const int xcd = bid & 7, idx = bid >> 3;
    const int ncn = nbn / sn;                    // chunk-cols
    const int cm = xcd / ncn, cn = xcd % ncn;
    const int lm = idx / sn,  ln = idx % sn;
    const long bm = (long)(cm * sm + lm) * 256;
    const long bn = (long)(cn * sn + ln) * (NF * 64);

    const int NT = K >> 6;
    const long strideB = (long)K * 2;            // bytes per global row
    const int srow = tid >> 3;                   // 0..63 row within 64-row chunk
    const int scb  = ((tid & 7) * 16) ^ ((srow & 7) << 4);   // pre-swizzled src byte

    auto stageA = [&](int t, int c) {            // c in 0..3
        unsigned short* base = &lds[(t & 1) * BUFE];
        const int row = c * 64 + srow;
        const char* src = (const char*)A + (bm + row) * strideB + (long)t * 128 + scb;
        gload_lds16(src, base + (c * 64 + wid * 8) * 64);
    };
    auto stageB = [&](int t, int c) {            // c in 0..NF-1
        unsigned short* base = &lds[(t & 1) * BUFE + 16384];
        const int row = c * 64 + srow;
        const char* src = (const char*)Bt + (bn + row) * strideB + (long)t * 128 + scb;
        gload_lds16(src, base + (c * 64 + wid * 8) * 64);
    };

    f32x4 acc[8][NF];
#pragma unroll
    for (int i = 0; i < 8; ++i)
#pragma unroll
        for (int j = 0; j < NF; ++j) acc[i][j] = f32x4{0.f, 0.f, 0.f, 0.f};

    // compute one K-tile: kk-outer so only one kk's fragments are live at once
    auto compute = [&](const unsigned short* Ab, const unsigned short* Bb) {
#pragma unroll
        for (int kk = 0; kk < 2; ++kk) {
            bf16x8 bfr[NF];
#pragma unroll
            for (int j = 0; j < NF; ++j) {
                const int row = wn * (NF * 16) + j * 16 + l16;
                const char* rb = (const char*)Bb + row * 128;
                bfr[j] = as_bf(*(const s16x8*)(rb + ((kk * 64 + l4 * 16) ^ ((l16 & 7) << 4))));
            }
#pragma unroll
            for (int half = 0; half < 2; ++half) {
                bf16x8 af[4];
#pragma unroll
                for (int i = 0; i < 4; ++i) {
                    const int row = wm * 128 + (half * 4 + i) * 16 + l16;
                    const char* rb = (const char*)Ab + row * 128;
                    af[i] = as_bf(*(const s16x8*)(rb + ((kk * 64 + l4 * 16) ^ ((l16 & 7) << 4))));
                }
                __builtin_amdgcn_s_setprio(1);
#pragma unroll
                for (int i = 0; i < 4; ++i)
#pragma unroll
                    for (int j = 0; j < NF; ++j)
                        acc[half * 4 + i][j] = __builtin_amdgcn_mfma_f32_16x16x32_bf16(
                            af[i], bfr[j], acc[half * 4 + i][j], 0, 0, 0);
                __builtin_amdgcn_s_setprio(0);
            }
        }
    };

    // prologue: stage tile 0 fully (4+NF loads/thread)
#pragma unroll
    for (int c = 0; c < 4; ++c) stageA(0, c);
#pragma unroll
    for (int c = 0; c < NF; ++c) stageB(0, c);

    for (int t = 0; t < NT - 1; ++t) {
        const unsigned short* Ab = &lds[(t & 1) * BUFE];
        const unsigned short* Bb = Ab + 16384;
#pragma unroll
        for (int c = 0; c < 4; ++c) stageA(t + 1, c);
#pragma unroll
        for (int c = 0; c < NF; ++c) stageB(t + 1, c);
        __builtin_amdgcn_sched_barrier(0);
        // counted wait: tile t's (4+NF) loads done, tile t+1's in flight
        if constexpr (NF == 6)      asm volatile("s_waitcnt vmcnt(10)" ::: "memory");
        else if constexpr (NF == 3) asm volatile("s_waitcnt vmcnt(7)" ::: "memory");
        else                        asm volatile("s_waitcnt vmcnt(6)" ::: "memory");
        __builtin_amdgcn_s_barrier();
        __builtin_amdgcn_sched_barrier(0);                 // no ds_read above validity
        compute(Ab, Bb);
        __builtin_amdgcn_s_barrier();   // all reads of buf done before t+2 staging
    }
    {
        const unsigned short* Ab = &lds[((NT - 1) & 1) * BUFE];
        const unsigned short* Bb = Ab + 16384;
        asm volatile("s_waitcnt vmcnt(0)" ::: "memory");
        __builtin_amdgcn_s_barrier();
        __builtin_amdgcn_sched_barrier(0);
        compute(Ab, Bb);
    }

    // bias per owned column
    float bvv[NF];
#pragma unroll
    for (int nf = 0; nf < NF; ++nf) {
        const long n = bn + wn * (NF * 16) + nf * 16 + l16;
        bvv[nf] = 0.f;
        if (hasBias)
            bvv[nf] = (n < HID) ? bq[n] : ((n < 2 * HID) ? bk[n - HID] : bv[n - 2 * HID]);
    }

    if constexpr (ROPE) {
        // fused RoPE epilogue: 4 row-chunks of 64; acc+bias -> LDS fp32 [64][385];
        // pairs (j, j+64) rotated in fp32; Q scaled by (1/sqrt(128))*log2(e);
        // V heads pass through. Coalesced bf16 stores (consecutive j -> n).
        constexpr int NH = NF / 2;               // whole heads per block (3 for NF=6)
        float* fl = (float*)lds;                 // reuse staging LDS (needs 64*385*4 B)
        const int jr = tid & 63;
        const int rquo = tid >> 6;               // 0..7
        const float inv = exp2f(-(float)jr * 0.20762050593046f);  // 10000^(-j/64)
#pragma unroll
        for (int c = 0; c < 4; ++c) {
            __builtin_amdgcn_s_barrier();        // prior chunk reads / final compute done
            if (wm == (c >> 1)) {
                const int mf0 = (c & 1) * 4;
#pragma unroll
                for (int mfi = 0; mfi < 4; ++mfi)
#pragma unroll
                    for (int r = 0; r < 4; ++r) {
                        const int rl = mfi * 16 + l4 * 4 + r;
#pragma unroll
                        for (int nf = 0; nf < NF; ++nf)
                            fl[rl * 385 + wn * (NF * 16) + nf * 16 + l16] =
                                acc[mf0 + mfi][nf][r] + bvv[nf];
                    }
            }
            __builtin_amdgcn_s_barrier();
#pragma unroll
            for (int rr = 0; rr < 8; ++rr) {
                const int rl = rr * 8 + rquo;
                const long m = bm + (c >> 1) * 128 + (c & 1) * 64 + rl;
                const int s = (int)(m & (SEQ - 1));
                float sn, cs;
                sincosf((float)s * inv, &sn, &cs);
#pragma unroll
                for (int hh = 0; hh < NH; ++hh) {
                    const long n = bn + hh * 128 + jr;
                    const bool ron = n < 2 * HID;          // rope Q,K; V passthrough
                    const float qsv = (n < HID) ? 0.12751744581845f : 1.0f;
                    const float se = ron ? sn : 0.f;
                    const float ce = ron ? cs : 1.f;
                    const float x1 = fl[rl * 385 + hh * 128 + jr];
                    const float x2 = fl[rl * 385 + hh * 128 + jr + 64];
                    Cb[m * (long)ldc + n]      = f2bf((x1 * ce - x2 * se) * qsv);
                    Cb[m * (long)ldc + n + 64] = f2bf((x2 * ce + x1 * se) * qsv);
                }
            }
        }
    } else {
        // plain epilogue: row-outer / nf-inner (write combining)
#pragma unroll
        for (int mf = 0; mf < 8; ++mf) {
#pragma unroll
            for (int r = 0; r < 4; ++r) {
                const long m = bm + wm * 128 + mf * 16 + l4 * 4 + r;
#pragma unroll
                for (int nf = 0; nf < NF; ++nf) {
                    const long n = bn + wn * (NF * 16) + nf * 16 + l16;
                    float v = acc[mf][nf][r] + bvv[nf];
                    if (F32OUT) Cf[m * (long)ldc + n] = v;
                    else        Cb[m * (long)ldc + n] = f2bf(v);
                }
            }
        }
    }
}

// ---------------- V[b,s,h,d] -> VT[b,h,d,s] ----------------
__global__ __launch_bounds__(256) void v_transpose(
    const unsigned short* __restrict__ qkv, unsigned short* __restrict__ vt)
{
    __shared__ unsigned short t[32][33];
    int bh = blockIdx.z;
    int b = bh >> 4, h = bh & 15;
    int s0 = blockIdx.x * 32, d0 = blockIdx.y * 32;
    int tx = threadIdx.x & 31, ty = threadIdx.x >> 5;
#pragma unroll
    for (int r = ty; r < 32; r += 8)
        t[r][tx] = qkv[(long)(b * SEQ + s0 + r) * QKN + 2 * HID + h * HD + d0 + tx];
    __syncthreads();
#pragma unroll
    for (int r = ty; r < 32; r += 8)
        vt[((long)bh * HD + d0 + r) * SEQ + s0 + tx] = t[tx][r];
}

// -------- MFMA flash attention: 8 waves / QBLK=128, T2 swizzles, dbuf staging,
// defer-max, swapped-QK^T in-register softmax, log2-domain exp2. XCD-chunked.
__global__ __launch_bounds__(512) void attn_kernel(
    const unsigned short* __restrict__ qkv,
    const unsigned short* __restrict__ vt,
    unsigned short* __restrict__ attnout)
{
    __shared__ unsigned short Ks[2][64 * 128];   // [kv][d], byte ^= (kv&7)<<4
    __shared__ unsigned short Vs[2][128 * 64];   // [d][kv], byte ^= (d&7)<<4

    const int tid = threadIdx.x, wid = tid >> 6, lane = tid & 63;
    const int l16 = lane & 15, l4 = lane >> 4;
    const int bid = blockIdx.x;                  // 0..511
    const int xcd = bid & 7, idx = bid >> 3;     // idx 0..63
    const int bh = xcd * 4 + (idx >> 4);         // 4 heads per XCD
    const int qt = idx & 15;                     // 16 q-tiles (QBLK=128)
    const int b = bh >> 4, h = bh & 15;
    const long rowbase = (long)b * SEQ;

    const unsigned short* Kg = &qkv[rowbase * QKN + HID + h * HD];  // + s*QKN
    const unsigned short* Vg = &vt[(long)bh * HD * SEQ];            // + d*SEQ

    // 16 K chunks + 16 V chunks over 8 waves -> 2+2 per wave
    auto stage = [&](int buf, int kv0) {
#pragma unroll
        for (int i = 0; i < 2; ++i) {
            int c = wid * 2 + i;
            int kr = c * 4 + l4;
            int kcb = (l16 * 16) ^ ((kr & 7) << 4);
            gload_lds16((const char*)(Kg + (long)(kv0 + kr) * QKN) + kcb, &Ks[buf][c * 512]);
            int vr = c * 8 + (lane >> 3);
            int vcb = ((lane & 7) * 16) ^ ((vr & 7) << 4);
            gload_lds16((const char*)(Vg + (long)vr * SEQ + kv0) + vcb, &Vs[buf][c * 512]);
        }
    };

    bf16x8 qf[4];
    {
        const long qrow = rowbase + qt * 128 + wid * 16 + l16;
        const unsigned short* qp = &qkv[qrow * QKN + h * HD];
#pragma unroll
        for (int kc = 0; kc < 4; ++kc) qf[kc] = ld_bf8(qp + kc * 32 + l4 * 8);
    }

    f32x4 o[8];
#pragma unroll
    for (int nb = 0; nb < 8; ++nb) o[nb] = f32x4{0.f, 0.f, 0.f, 0.f};
    float mrun = -3.0e38f, lrun = 0.f;       // per-lane scalars (q = l16), log2 units

    const int srcA = ((l4 & 1) * 2) * 16 + l16;   // lane of l4_s = 2(l4&1)
    const int srcB = srcA + 16;                   // lane of l4_s = 2(l4&1)+1
    const bool sel = (l4 >> 1) != 0;              // nf_s = 2kc + (l4>>1)

    stage(0, 0);
    __syncthreads();

    for (int t = 0; t < SEQ / 64; ++t) {
        const int cur = t & 1;
        if (t < SEQ / 64 - 1) stage(cur ^ 1, (t + 1) * 64);
        __builtin_amdgcn_sched_barrier(0);   // pin: issue next-tile stage first

        const unsigned short* Kc = &Ks[cur][0];
        const unsigned short* Vc = &Vs[cur][0];

        // S^T = K Q^T (log2 domain): A = kf (rows=kv), B = qf (cols=q)
        f32x4 sc[4];
#pragma unroll
        for (int nf = 0; nf < 4; ++nf) sc[nf] = f32x4{0.f, 0.f, 0.f, 0.f};
#pragma unroll
        for (int kc = 0; kc < 4; ++kc) {
#pragma unroll
            for (int nf = 0; nf < 4; ++nf) {
                int row = nf * 16 + l16;
                int cb = (kc * 64 + l4 * 16) ^ ((row & 7) << 4);
                bf16x8 kf = as_bf(*(const s16x8*)((const char*)Kc + row * 256 + cb));
                sc[nf] = __builtin_amdgcn_mfma_f32_16x16x32_bf16(kf, qf[kc], sc[nf], 0, 0, 0);
            }
        }

        // per-lane max over 16 values via max3 tree, then combine 4 l4-copies
        float m0 = fmaxf(fmaxf(sc[0][0], sc[0][1]), sc[0][2]);
        float m1 = fmaxf(fmaxf(sc[0][3], sc[1][0]), sc[1][1]);
        float m2 = fmaxf(fmaxf(sc[1][2], sc[1][3]), sc[2][0]);
        float m3 = fmaxf(fmaxf(sc[2][1], sc[2][2]), sc[2][3]);
        float m4 = fmaxf(fmaxf(sc[3][0], sc[3][1]), sc[3][2]);
        float tmax = fmaxf(fmaxf(m0, m1), m2);
        tmax = fmaxf(fmaxf(m3, m4), tmax);
        tmax = fmaxf(tmax, sc[3][3]);
        tmax = fmaxf(tmax, __shfl_xor(tmax, 16, 64));
        tmax = fmaxf(tmax, __shfl_xor(tmax, 32, 64));

        // defer-max (T13, log2 units): skip rescale when growth <= 8
        if (!__all(tmax - mrun <= 8.0f)) {
            float mn = fmaxf(mrun, tmax);
            float sc_ = exp2f(mrun - mn);
            mrun = mn;
            lrun *= sc_;
            float s_[4];
#pragma unroll
            for (int r = 0; r < 4; ++r) s_[r] = __shfl(sc_, l4 * 4 + r, 64);
#pragma unroll
            for (int nb = 0; nb < 8; ++nb)
#pragma unroll
                for (int r = 0; r < 4; ++r) o[nb][r] *= s_[r];
        }

        // P = exp2(S - m); pack to bf16 pairs; sum
        unsigned pk[4][2];
        float sum = 0.f;
#pragma unroll
        for (int nf = 0; nf < 4; ++nf) {
            float p0 = exp2f(sc[nf][0] - mrun);
            float p1 = exp2f(sc[nf][1] - mrun);
            float p2 = exp2f(sc[nf][2] - mrun);
            float p3 = exp2f(sc[nf][3] - mrun);
            sum += (p0 + p1) + (p2 + p3);
            union { __bf16 b[2]; unsigned u; } w0, w1;
            w0.b[0] = (__bf16)p0; w0.b[1] = (__bf16)p1;
            w1.b[0] = (__bf16)p2; w1.b[1] = (__bf16)p3;
            pk[nf][0] = w0.u; pk[nf][1] = w1.u;
        }
        sum += __shfl_xor(sum, 16, 64);
        sum += __shfl_xor(sum, 32, 64);
        lrun += sum;

        // redistribute P into PV A-fragments (4-lane group exchange)
        union { unsigned u[4]; bf16x8 v; } pa0, pa1;
#pragma unroll
        for (int w = 0; w < 2; ++w) {
            unsigned a0 = __shfl(pk[0][w], srcA, 64);
            unsigned a1 = __shfl(pk[1][w], srcA, 64);
            unsigned b0 = __shfl(pk[0][w], srcB, 64);
            unsigned b1 = __shfl(pk[1][w], srcB, 64);
            pa0.u[w]     = sel ? a1 : a0;
            pa0.u[2 + w] = sel ? b1 : b0;
            unsigned c0 = __shfl(pk[2][w], srcA, 64);
            unsigned c1 = __shfl(pk[3][w], srcA, 64);
            unsigned d0 = __shfl(pk[2][w], srcB, 64);
            unsigned d1 = __shfl(pk[3][w], srcB, 64);
            pa1.u[w]     = sel ? c1 : c0;
            pa1.u[2 + w] = sel ? d1 : d0;
        }

        // O += P V   (A = pa (q rows), B = V^T [d][kv] swizzled)
#pragma unroll
        for (int kc = 0; kc < 2; ++kc) {
            bf16x8 pav = kc ? pa1.v : pa0.v;
#pragma unroll
            for (int nb = 0; nb < 8; ++nb) {
                int vrow = nb * 16 + l16;
                int vcb = (kc * 64 + l4 * 16) ^ ((vrow & 7) << 4);
                bf16x8 vb = as_bf(*(const s16x8*)((const char*)Vc + vrow * 128 + vcb));
                o[nb] = __builtin_amdgcn_mfma_f32_16x16x32_bf16(pav, vb, o[nb], 0, 0, 0);
            }
        }
        __syncthreads();   // implicit vmcnt(0): next-tile stage (issued pre-compute) done
    }

    // stats live at q=l16 lanes; o rows are q=l4*4+r -> hop via 4 shuffles
    float linv = 1.f / lrun;
    float li[4];
#pragma unroll
    for (int r = 0; r < 4; ++r) li[r] = __shfl(linv, l4 * 4 + r, 64);
#pragma unroll
    for (int r = 0; r < 4; ++r) {
        long m = rowbase + qt * 128 + wid * 16 + l4 * 4 + r;
#pragma unroll
        for (int nb = 0; nb < 8; ++nb)
            attnout[m * HID + h * HD + nb * 16 + l16] = f2bf(o[nb][r] * li[r]);
    }
}

// ---------------- launch ----------------
extern "C" void kernel_launch(void* const* d_in, const int* in_sizes, int n_in,
                              void* d_out, int out_size, void* d_ws, size_t ws_size,
                              hipStream_t stream)
{
    const float* hs = (const float*)d_in[0];
    const float* Wq = (const float*)d_in[1];
    const float* bq = (const float*)d_in[2];
    const float* Wk = (const float*)d_in[3];
    const float* bk = (const float*)d_in[4];
    const float* Wv = (const float*)d_in[5];
    const float* bv = (const float*)d_in[6];
    const float* Wo = (const float*)d_in[7];
    float* out = (float*)d_out;   // fp32 output (confirmed round 5)

    bool shapes_ok =
        (n_in == 8) && (out_size == 8388608) &&
        in_sizes[0] == 8388608 && in_sizes[1] == 4194304 && in_sizes[2] == 2048 &&
        in_sizes[3] == 4194304 && in_sizes[4] == 2048 && in_sizes[5] == 4194304 &&
        in_sizes[6] == 2048 && in_sizes[7] == 4194304;
    if (!shapes_ok || ws_size < 117440512ull) {
        fill_f32<<<32768, 256, 0, stream>>>(out, shapes_ok ? 1000.f : 0.f, out_size);
        return;
    }

    char* ws = (char*)d_ws;
    unsigned short* hsB     = (unsigned short*)(ws);              // [4096][2048] bf16
    unsigned short* qkvB    = (unsigned short*)(ws + 16777216);   // [4096][6144] bf16
    unsigned short* wqkvT   = (unsigned short*)(ws + 67108864);   // [6144][2048] bf16
    unsigned short* vtB     = (unsigned short*)(ws + 92274688);   // [32][128][2048] bf16
    unsigned short* woT     = (unsigned short*)(ws + 109051904);  // [2048][2048] bf16
    unsigned short* attnout = hsB;   // hsB dead after QKV GEMM

    convert_f32_bf16<<<4096, 256, 0, stream>>>(hs, hsB);
    dim3 tg(64, 64);
    transpose_w<<<tg, 256, 0, stream>>>(Wq, wqkvT);
    transpose_w<<<tg, 256, 0, stream>>>(Wk, wqkvT + 2048 * 2048);
    transpose_w<<<tg, 256, 0, stream>>>(Wv, wqkvT + 2 * 2048 * 2048);
    transpose_w<<<tg, 256, 0, stream>>>(Wo, woT);

    // QKV fat-wave + fused RoPE epilogue: 256x384 tiles -> 256 blocks = 1 round
    gemm_8phase<6, false, true><<<dim3(256), 512, 0, stream>>>(
        hsB, wqkvT, bq, bk, bv, qkvB, nullptr, 2048, QKN, 16, 8, 4, 1);
    v_transpose<<<dim3(64, 4, 32), 256, 0, stream>>>(qkvB, vtB);
    // attn: QBLK=128, 8 waves, 512 blocks, XCD-chunked (4 heads x 16 qt per XCD)
    attn_kernel<<<dim3(512), 512, 0, stream>>>(qkvB, vtB, attnout);
    // out-proj: 256x128 tiles, 16x16 grid, XCD chunks 4x8, fp32 out
    gemm_8phase<2, true, false><<<dim3(256), 512, 0, stream>>>(
        attnout, woT, nullptr, nullptr, nullptr, nullptr, out, 2048, HID, 16, 4, 8, 0);
}

// Round 20
// 295.702 us; speedup vs baseline: 1.0634x; 1.0069x over previous
//
#include <hip/hip_runtime.h>

#define HID 2048
#define SEQ 2048
#define HD 128
#define QKN 6144      // 3*HID

typedef float f32x4 __attribute__((ext_vector_type(4)));
typedef short s16x8 __attribute__((ext_vector_type(8)));
typedef __bf16 bf16x8 __attribute__((ext_vector_type(8)));

static __device__ __forceinline__ unsigned short f2bf(float x) {
    unsigned u = __float_as_uint(x);
    u = u + 0x7FFFu + ((u >> 16) & 1u);   // RNE
    return (unsigned short)(u >> 16);
}
static __device__ __forceinline__ float bf2f(unsigned short h) {
    return __uint_as_float(((unsigned)h) << 16);
}
static __device__ __forceinline__ bf16x8 as_bf(s16x8 v) {
    union { s16x8 s; bf16x8 b; } u; u.s = v; return u.b;
}
static __device__ __forceinline__ bf16x8 ld_bf8(const unsigned short* p) {
    return as_bf(*(const s16x8*)p);
}
// async global->LDS, 16B/lane; LDS dest = wave-uniform base + lane*16 (m104)
static __device__ __forceinline__ void gload_lds16(const void* g, void* l) {
    __builtin_amdgcn_global_load_lds(
        (const __attribute__((address_space(1))) void*)g,
        (__attribute__((address_space(3))) void*)l,
        16, 0, 0);
}

__global__ __launch_bounds__(256) void fill_f32(
    float* __restrict__ out, float v, int n)
{
    int i = blockIdx.x * 256 + threadIdx.x;
    if (i < n) out[i] = v;
}

// ---------------- fp32 -> bf16 convert (8 elems/thread) ----------------
__global__ __launch_bounds__(256) void convert_f32_bf16(
    const float* __restrict__ in, unsigned short* __restrict__ out)
{
    long i = ((long)blockIdx.x * 256 + threadIdx.x) * 8;
    f32x4 a = *(const f32x4*)&in[i];
    f32x4 b = *(const f32x4*)&in[i + 4];
    s16x8 o;
#pragma unroll
    for (int e = 0; e < 4; ++e) {
        o[e]     = (short)f2bf(a[e]);
        o[e + 4] = (short)f2bf(b[e]);
    }
    *(s16x8*)&out[i] = o;
}

// ------- batched W[k][n] fp32 -> Wt[n][k] bf16 (r20: 4 matrices, z selects) ----
__global__ __launch_bounds__(256) void transpose_w4(
    const float* __restrict__ Wq, const float* __restrict__ Wk,
    const float* __restrict__ Wv, const float* __restrict__ Wo,
    unsigned short* __restrict__ wqkvT, unsigned short* __restrict__ woT)
{
    __shared__ float t[32][33];
    const int z = blockIdx.z;
    const float* W = (z == 0) ? Wq : (z == 1) ? Wk : (z == 2) ? Wv : Wo;
    unsigned short* Wt = (z < 3) ? (wqkvT + (long)z * HID * HID) : woT;
    int k0 = blockIdx.x * 32, n0 = blockIdx.y * 32;
    int tx = threadIdx.x & 31, ty = threadIdx.x >> 5;
#pragma unroll
    for (int r = ty; r < 32; r += 8)
        t[r][tx] = W[(long)(k0 + r) * HID + n0 + tx];
    __syncthreads();
#pragma unroll
    for (int r = ty; r < 32; r += 8)
        Wt[(long)(n0 + r) * HID + k0 + tx] = f2bf(t[tx][r]);
}

// ======== 256x(NF*64) single-phase GEMM, fat-wave: wave-tile 128 x NF*16 ====
// dbuf LDS; counted vmcnt(4+NF); setprio; 2-D XCD chunking; write-combined
// epilogue. ROPE=true (QKV): rope fused into epilogue via LDS pair-exchange.
template<int NF, bool F32OUT, bool ROPE>
__global__ __launch_bounds__(512, 2) void gemm_8phase(
    const unsigned short* __restrict__ A,    // [M][K] bf16
    const unsigned short* __restrict__ Bt,   // [N][K] bf16
    const float* __restrict__ bq, const float* __restrict__ bk,
    const float* __restrict__ bv,
    unsigned short* __restrict__ Cb, float* __restrict__ Cf,
    int K, int ldc, int nbn, int sm, int sn, int hasBias)
{
    constexpr int BUFE = 16384 + NF * 4096;      // elems per LDS buffer (A|B)
    __shared__ unsigned short lds[2 * BUFE];
    const int tid = threadIdx.x;
    const int wid = tid >> 6, lane = tid & 63;
    const int l16 = lane & 15, l4 = lane >> 4;
    const int wm = wid >> 2, wn = wid & 3;

    // 2-D XCD chunk decode: 8 chunks of sm x sn tiles
    const int bid = blockIdx.x;
    const int xcd = bid & 7, idx = bid >> 3;
    const int ncn = nbn / sn;                    // chunk-cols
    const int cm = xcd / ncn, cn = xcd % ncn;
    const int lm = idx / sn,  ln = idx % sn;
    const long bm = (long)(cm * sm + lm) * 256;
    const long bn = (long)(cn * sn + ln) * (NF * 64);

    const int NT = K >> 6;
    const long strideB = (long)K * 2;            // bytes per global row
    const int srow = tid >> 3;                   // 0..63 row within 64-row chunk
    const int scb  = ((tid & 7) * 16) ^ ((srow & 7) << 4);   // pre-swizzled src byte

    auto stageA = [&](int t, int c) {            // c in 0..3
        unsigned short* base = &lds[(t & 1) * BUFE];
        const int row = c * 64 + srow;
        const char* src = (const char*)A + (bm + row) * strideB + (long)t * 128 + scb;
        gload_lds16(src, base + (c * 64 + wid * 8) * 64);
    };
    auto stageB = [&](int t, int c) {            // c in 0..NF-1
        unsigned short* base = &lds[(t & 1) * BUFE + 16384];
        const int row = c * 64 + srow;
        const char* src = (const char*)Bt + (bn + row) * strideB + (long)t * 128 + scb;
        gload_lds16(src, base + (c * 64 + wid * 8) * 64);
    };

    f32x4 acc[8][NF];
#pragma unroll
    for (int i = 0; i < 8; ++i)
#pragma unroll
        for (int j = 0; j < NF; ++j) acc[i][j] = f32x4{0.f, 0.f, 0.f, 0.f};

    // compute one K-tile: kk-outer so only one kk's fragments are live at once
    auto compute = [&](const unsigned short* Ab, const unsigned short* Bb) {
#pragma unroll
        for (int kk = 0; kk < 2; ++kk) {
            bf16x8 bfr[NF];
#pragma unroll
            for (int j = 0; j < NF; ++j) {
                const int row = wn * (NF * 16) + j * 16 + l16;
                const char* rb = (const char*)Bb + row * 128;
                bfr[j] = as_bf(*(const s16x8*)(rb + ((kk * 64 + l4 * 16) ^ ((l16 & 7) << 4))));
            }
#pragma unroll
            for (int half = 0; half < 2; ++half) {
                bf16x8 af[4];
#pragma unroll
                for (int i = 0; i < 4; ++i) {
                    const int row = wm * 128 + (half * 4 + i) * 16 + l16;
                    const char* rb = (const char*)Ab + row * 128;
                    af[i] = as_bf(*(const s16x8*)(rb + ((kk * 64 + l4 * 16) ^ ((l16 & 7) << 4))));
                }
                __builtin_amdgcn_s_setprio(1);
#pragma unroll
                for (int i = 0; i < 4; ++i)
#pragma unroll
                    for (int j = 0; j < NF; ++j)
                        acc[half * 4 + i][j] = __builtin_amdgcn_mfma_f32_16x16x32_bf16(
                            af[i], bfr[j], acc[half * 4 + i][j], 0, 0, 0);
                __builtin_amdgcn_s_setprio(0);
            }
        }
    };

    // prologue: stage tile 0 fully (4+NF loads/thread)
#pragma unroll
    for (int c = 0; c < 4; ++c) stageA(0, c);
#pragma unroll
    for (int c = 0; c < NF; ++c) stageB(0, c);

    for (int t = 0; t < NT - 1; ++t) {
        const unsigned short* Ab = &lds[(t & 1) * BUFE];
        const unsigned short* Bb = Ab + 16384;
#pragma unroll
        for (int c = 0; c < 4; ++c) stageA(t + 1, c);
#pragma unroll
        for (int c = 0; c < NF; ++c) stageB(t + 1, c);
        __builtin_amdgcn_sched_barrier(0);
        // counted wait: tile t's (4+NF) loads done, tile t+1's in flight
        if constexpr (NF == 6)      asm volatile("s_waitcnt vmcnt(10)" ::: "memory");
        else if constexpr (NF == 3) asm volatile("s_waitcnt vmcnt(7)" ::: "memory");
        else                        asm volatile("s_waitcnt vmcnt(6)" ::: "memory");
        __builtin_amdgcn_s_barrier();
        __builtin_amdgcn_sched_barrier(0);                 // no ds_read above validity
        compute(Ab, Bb);
        __builtin_amdgcn_s_barrier();   // all reads of buf done before t+2 staging
    }
    {
        const unsigned short* Ab = &lds[((NT - 1) & 1) * BUFE];
        const unsigned short* Bb = Ab + 16384;
        asm volatile("s_waitcnt vmcnt(0)" ::: "memory");
        __builtin_amdgcn_s_barrier();
        __builtin_amdgcn_sched_barrier(0);
        compute(Ab, Bb);
    }

    // bias per owned column
    float bvv[NF];
#pragma unroll
    for (int nf = 0; nf < NF; ++nf) {
        const long n = bn + wn * (NF * 16) + nf * 16 + l16;
        bvv[nf] = 0.f;
        if (hasBias)
            bvv[nf] = (n < HID) ? bq[n] : ((n < 2 * HID) ? bk[n - HID] : bv[n - 2 * HID]);
    }

    if constexpr (ROPE) {
        // fused RoPE epilogue: 4 row-chunks of 64; acc+bias -> LDS fp32 [64][385];
        // pairs (j, j+64) rotated in fp32; Q scaled by (1/sqrt(128))*log2(e);
        // V heads pass through. Coalesced bf16 stores.
        constexpr int NH = NF / 2;               // whole heads per block (3 for NF=6)
        float* fl = (float*)lds;                 // reuse staging LDS (64*385*4 B)
        const int jr = tid & 63;
        const int rquo = tid >> 6;               // 0..7
        const float inv = exp2f(-(float)jr * 0.20762050593046f);  // 10000^(-j/64)
#pragma unroll
        for (int c = 0; c < 4; ++c) {
            __builtin_amdgcn_s_barrier();        // prior chunk reads / final compute done
            if (wm == (c >> 1)) {
                const int mf0 = (c & 1) * 4;
#pragma unroll
                for (int mfi = 0; mfi < 4; ++mfi)
#pragma unroll
                    for (int r = 0; r < 4; ++r) {
                        const int rl = mfi * 16 + l4 * 4 + r;
#pragma unroll
                        for (int nf = 0; nf < NF; ++nf)
                            fl[rl * 385 + wn * (NF * 16) + nf * 16 + l16] =
                                acc[mf0 + mfi][nf][r] + bvv[nf];
                    }
            }
            __builtin_amdgcn_s_barrier();
#pragma unroll
            for (int rr = 0; rr < 8; ++rr) {
                const int rl = rr * 8 + rquo;
                const long m = bm + (c >> 1) * 128 + (c & 1) * 64 + rl;
                const int s = (int)(m & (SEQ - 1));
                float sn, cs;
                sincosf((float)s * inv, &sn, &cs);
#pragma unroll
                for (int hh = 0; hh < NH; ++hh) {
                    const long n = bn + hh * 128 + jr;
                    const bool ron = n < 2 * HID;          // rope Q,K; V passthrough
                    const float qsv = (n < HID) ? 0.12751744581845f : 1.0f;
                    const float se = ron ? sn : 0.f;
                    const float ce = ron ? cs : 1.f;
                    const float x1 = fl[rl * 385 + hh * 128 + jr];
                    const float x2 = fl[rl * 385 + hh * 128 + jr + 64];
                    Cb[m * (long)ldc + n]      = f2bf((x1 * ce - x2 * se) * qsv);
                    Cb[m * (long)ldc + n + 64] = f2bf((x2 * ce + x1 * se) * qsv);
                }
            }
        }
    } else {
        // plain epilogue: row-outer / nf-inner (write combining)
#pragma unroll
        for (int mf = 0; mf < 8; ++mf) {
#pragma unroll
            for (int r = 0; r < 4; ++r) {
                const long m = bm + wm * 128 + mf * 16 + l4 * 4 + r;
#pragma unroll
                for (int nf = 0; nf < NF; ++nf) {
                    const long n = bn + wn * (NF * 16) + nf * 16 + l16;
                    float v = acc[mf][nf][r] + bvv[nf];
                    if (F32OUT) Cf[m * (long)ldc + n] = v;
                    else        Cb[m * (long)ldc + n] = f2bf(v);
                }
            }
        }
    }
}

// ---------------- V[b,s,h,d] -> VT[b,h,d,s] ----------------
__global__ __launch_bounds__(256) void v_transpose(
    const unsigned short* __restrict__ qkv, unsigned short* __restrict__ vt)
{
    __shared__ unsigned short t[32][33];
    int bh = blockIdx.z;
    int b = bh >> 4, h = bh & 15;
    int s0 = blockIdx.x * 32, d0 = blockIdx.y * 32;
    int tx = threadIdx.x & 31, ty = threadIdx.x >> 5;
#pragma unroll
    for (int r = ty; r < 32; r += 8)
        t[r][tx] = qkv[(long)(b * SEQ + s0 + r) * QKN + 2 * HID + h * HD + d0 + tx];
    __syncthreads();
#pragma unroll
    for (int r = ty; r < 32; r += 8)
        vt[((long)bh * HD + d0 + r) * SEQ + s0 + tx] = t[tx][r];
}

// -------- MFMA flash attention: 8 waves / QBLK=128, T2 swizzles, dbuf staging,
// defer-max, swapped-QK^T in-register softmax, log2-domain exp2. XCD-chunked.
// r20: T5 setprio around both MFMA clusters (16 resident waves at diverse
// phases -> scheduler favors MFMA-entering wave; +4-7% measured on attn, m191).
__global__ __launch_bounds__(512) void attn_kernel(
    const unsigned short* __restrict__ qkv,
    const unsigned short* __restrict__ vt,
    unsigned short* __restrict__ attnout)
{
    __shared__ unsigned short Ks[2][64 * 128];   // [kv][d], byte ^= (kv&7)<<4
    __shared__ unsigned short Vs[2][128 * 64];   // [d][kv], byte ^= (d&7)<<4

    const int tid = threadIdx.x, wid = tid >> 6, lane = tid & 63;
    const int l16 = lane & 15, l4 = lane >> 4;
    const int bid = blockIdx.x;                  // 0..511
    const int xcd = bid & 7, idx = bid >> 3;     // idx 0..63
    const int bh = xcd * 4 + (idx >> 4);         // 4 heads per XCD
    const int qt = idx & 15;                     // 16 q-tiles (QBLK=128)
    const int b = bh >> 4, h = bh & 15;
    const long rowbase = (long)b * SEQ;

    const unsigned short* Kg = &qkv[rowbase * QKN + HID + h * HD];  // + s*QKN
    const unsigned short* Vg = &vt[(long)bh * HD * SEQ];            // + d*SEQ

    // 16 K chunks + 16 V chunks over 8 waves -> 2+2 per wave
    auto stage = [&](int buf, int kv0) {
#pragma unroll
        for (int i = 0; i < 2; ++i) {
            int c = wid * 2 + i;
            int kr = c * 4 + l4;
            int kcb = (l16 * 16) ^ ((kr & 7) << 4);
            gload_lds16((const char*)(Kg + (long)(kv0 + kr) * QKN) + kcb, &Ks[buf][c * 512]);
            int vr = c * 8 + (lane >> 3);
            int vcb = ((lane & 7) * 16) ^ ((vr & 7) << 4);
            gload_lds16((const char*)(Vg + (long)vr * SEQ + kv0) + vcb, &Vs[buf][c * 512]);
        }
    };

    bf16x8 qf[4];
    {
        const long qrow = rowbase + qt * 128 + wid * 16 + l16;
        const unsigned short* qp = &qkv[qrow * QKN + h * HD];
#pragma unroll
        for (int kc = 0; kc < 4; ++kc) qf[kc] = ld_bf8(qp + kc * 32 + l4 * 8);
    }

    f32x4 o[8];
#pragma unroll
    for (int nb = 0; nb < 8; ++nb) o[nb] = f32x4{0.f, 0.f, 0.f, 0.f};
    float mrun = -3.0e38f, lrun = 0.f;       // per-lane scalars (q = l16), log2 units

    const int srcA = ((l4 & 1) * 2) * 16 + l16;   // lane of l4_s = 2(l4&1)
    const int srcB = srcA + 16;                   // lane of l4_s = 2(l4&1)+1
    const bool sel = (l4 >> 1) != 0;              // nf_s = 2kc + (l4>>1)

    stage(0, 0);
    __syncthreads();

    for (int t = 0; t < SEQ / 64; ++t) {
        const int cur = t & 1;
        if (t < SEQ / 64 - 1) stage(cur ^ 1, (t + 1) * 64);
        __builtin_amdgcn_sched_barrier(0);   // pin: issue next-tile stage first

        const unsigned short* Kc = &Ks[cur][0];
        const unsigned short* Vc = &Vs[cur][0];

        // S^T = K Q^T (log2 domain): A = kf (rows=kv), B = qf (cols=q)
        f32x4 sc[4];
#pragma unroll
        for (int nf = 0; nf < 4; ++nf) sc[nf] = f32x4{0.f, 0.f, 0.f, 0.f};
        __builtin_amdgcn_s_setprio(1);
#pragma unroll
        for (int kc = 0; kc < 4; ++kc) {
#pragma unroll
            for (int nf = 0; nf < 4; ++nf) {
                int row = nf * 16 + l16;
                int cb = (kc * 64 + l4 * 16) ^ ((row & 7) << 4);
                bf16x8 kf = as_bf(*(const s16x8*)((const char*)Kc + row * 256 + cb));
                sc[nf] = __builtin_amdgcn_mfma_f32_16x16x32_bf16(kf, qf[kc], sc[nf], 0, 0, 0);
            }
        }
        __builtin_amdgcn_s_setprio(0);

        // per-lane max over 16 values via max3 tree, then combine 4 l4-copies
        float m0 = fmaxf(fmaxf(sc[0][0], sc[0][1]), sc[0][2]);
        float m1 = fmaxf(fmaxf(sc[0][3], sc[1][0]), sc[1][1]);
        float m2 = fmaxf(fmaxf(sc[1][2], sc[1][3]), sc[2][0]);
        float m3 = fmaxf(fmaxf(sc[2][1], sc[2][2]), sc[2][3]);
        float m4 = fmaxf(fmaxf(sc[3][0], sc[3][1]), sc[3][2]);
        float tmax = fmaxf(fmaxf(m0, m1), m2);
        tmax = fmaxf(fmaxf(m3, m4), tmax);
        tmax = fmaxf(tmax, sc[3][3]);
        tmax = fmaxf(tmax, __shfl_xor(tmax, 16, 64));
        tmax = fmaxf(tmax, __shfl_xor(tmax, 32, 64));

        // defer-max (T13, log2 units): skip rescale when growth <= 8
        if (!__all(tmax - mrun <= 8.0f)) {
            float mn = fmaxf(mrun, tmax);
            float sc_ = exp2f(mrun - mn);
            mrun = mn;
            lrun *= sc_;
            float s_[4];
#pragma unroll
            for (int r = 0; r < 4; ++r) s_[r] = __shfl(sc_, l4 * 4 + r, 64);
#pragma unroll
            for (int nb = 0; nb < 8; ++nb)
#pragma unroll
                for (int r = 0; r < 4; ++r) o[nb][r] *= s_[r];
        }

        // P = exp2(S - m); pack to bf16 pairs; sum
        unsigned pk[4][2];
        float sum = 0.f;
#pragma unroll
        for (int nf = 0; nf < 4; ++nf) {
            float p0 = exp2f(sc[nf][0] - mrun);
            float p1 = exp2f(sc[nf][1] - mrun);
            float p2 = exp2f(sc[nf][2] - mrun);
            float p3 = exp2f(sc[nf][3] - mrun);
            sum += (p0 + p1) + (p2 + p3);
            union { __bf16 b[2]; unsigned u; } w0, w1;
            w0.b[0] = (__bf16)p0; w0.b[1] = (__bf16)p1;
            w1.b[0] = (__bf16)p2; w1.b[1] = (__bf16)p3;
            pk[nf][0] = w0.u; pk[nf][1] = w1.u;
        }
        sum += __shfl_xor(sum, 16, 64);
        sum += __shfl_xor(sum, 32, 64);
        lrun += sum;

        // redistribute P into PV A-fragments (4-lane group exchange)
        union { unsigned u[4]; bf16x8 v; } pa0, pa1;
#pragma unroll
        for (int w = 0; w < 2; ++w) {
            unsigned a0 = __shfl(pk[0][w], srcA, 64);
            unsigned a1 = __shfl(pk[1][w], srcA, 64);
            unsigned b0 = __shfl(pk[0][w], srcB, 64);
            unsigned b1 = __shfl(pk[1][w], srcB, 64);
            pa0.u[w]     = sel ? a1 : a0;
            pa0.u[2 + w] = sel ? b1 : b0;
            unsigned c0 = __shfl(pk[2][w], srcA, 64);
            unsigned c1 = __shfl(pk[3][w], srcA, 64);
            unsigned d0 = __shfl(pk[2][w], srcB, 64);
            unsigned d1 = __shfl(pk[3][w], srcB, 64);
            pa1.u[w]     = sel ? c1 : c0;
            pa1.u[2 + w] = sel ? d1 : d0;
        }

        // O += P V   (A = pa (q rows), B = V^T [d][kv] swizzled)
        __builtin_amdgcn_s_setprio(1);
#pragma unroll
        for (int kc = 0; kc < 2; ++kc) {
            bf16x8 pav = kc ? pa1.v : pa0.v;
#pragma unroll
            for (int nb = 0; nb < 8; ++nb) {
                int vrow = nb * 16 + l16;
                int vcb = (kc * 64 + l4 * 16) ^ ((vrow & 7) << 4);
                bf16x8 vb = as_bf(*(const s16x8*)((const char*)Vc + vrow * 128 + vcb));
                o[nb] = __builtin_amdgcn_mfma_f32_16x16x32_bf16(pav, vb, o[nb], 0, 0, 0);
            }
        }
        __builtin_amdgcn_s_setprio(0);
        __syncthreads();   // implicit vmcnt(0): next-tile stage (issued pre-compute) done
    }

    // stats live at q=l16 lanes; o rows are q=l4*4+r -> hop via 4 shuffles
    float linv = 1.f / lrun;
    float li[4];
#pragma unroll
    for (int r = 0; r < 4; ++r) li[r] = __shfl(linv, l4 * 4 + r, 64);
#pragma unroll
    for (int r = 0; r < 4; ++r) {
        long m = rowbase + qt * 128 + wid * 16 + l4 * 4 + r;
#pragma unroll
        for (int nb = 0; nb < 8; ++nb)
            attnout[m * HID + h * HD + nb * 16 + l16] = f2bf(o[nb][r] * li[r]);
    }
}

// ---------------- launch ----------------
extern "C" void kernel_launch(void* const* d_in, const int* in_sizes, int n_in,
                              void* d_out, int out_size, void* d_ws, size_t ws_size,
                              hipStream_t stream)
{
    const float* hs = (const float*)d_in[0];
    const float* Wq = (const float*)d_in[1];
    const float* bq = (const float*)d_in[2];
    const float* Wk = (const float*)d_in[3];
    const float* bk = (const float*)d_in[4];
    const float* Wv = (const float*)d_in[5];
    const float* bv = (const float*)d_in[6];
    const float* Wo = (const float*)d_in[7];
    float* out = (float*)d_out;   // fp32 output (confirmed round 5)

    bool shapes_ok =
        (n_in == 8) && (out_size == 8388608) &&
        in_sizes[0] == 8388608 && in_sizes[1] == 4194304 && in_sizes[2] == 2048 &&
        in_sizes[3] == 4194304 && in_sizes[4] == 2048 && in_sizes[5] == 4194304 &&
        in_sizes[6] == 2048 && in_sizes[7] == 4194304;
    if (!shapes_ok || ws_size < 117440512ull) {
        fill_f32<<<32768, 256, 0, stream>>>(out, shapes_ok ? 1000.f : 0.f, out_size);
        return;
    }

    char* ws = (char*)d_ws;
    unsigned short* hsB     = (unsigned short*)(ws);              // [4096][2048] bf16
    unsigned short* qkvB    = (unsigned short*)(ws + 16777216);   // [4096][6144] bf16
    unsigned short* wqkvT   = (unsigned short*)(ws + 67108864);   // [6144][2048] bf16
    unsigned short* vtB     = (unsigned short*)(ws + 92274688);   // [32][128][2048] bf16
    unsigned short* woT     = (unsigned short*)(ws + 109051904);  // [2048][2048] bf16
    unsigned short* attnout = hsB;   // hsB dead after QKV GEMM

    convert_f32_bf16<<<4096, 256, 0, stream>>>(hs, hsB);
    transpose_w4<<<dim3(64, 64, 4), 256, 0, stream>>>(Wq, Wk, Wv, Wo, wqkvT, woT);

    // QKV fat-wave + fused RoPE epilogue: 256x384 tiles -> 256 blocks = 1 round
    gemm_8phase<6, false, true><<<dim3(256), 512, 0, stream>>>(
        hsB, wqkvT, bq, bk, bv, qkvB, nullptr, 2048, QKN, 16, 8, 4, 1);
    v_transpose<<<dim3(64, 4, 32), 256, 0, stream>>>(qkvB, vtB);
    // attn: QBLK=128, 8 waves, 512 blocks, XCD-chunked (4 heads x 16 qt per XCD)
    attn_kernel<<<dim3(512), 512, 0, stream>>>(qkvB, vtB, attnout);
    // out-proj: 256x128 tiles, 16x16 grid, XCD chunks 4x8, fp32 out
    gemm_8phase<2, true, false><<<dim3(256), 512, 0, stream>>>(
        attnout, woT, nullptr, nullptr, nullptr, nullptr, out, 2048, HID, 16, 4, 8, 0);
}

// Round 21
// 293.329 us; speedup vs baseline: 1.0720x; 1.0081x over previous
//
#include <hip/hip_runtime.h>

#define HID 2048
#define SEQ 2048
#define HD 128
#define QKN 6144      // 3*HID

typedef float f32x4 __attribute__((ext_vector_type(4)));
typedef short s16x8 __attribute__((ext_vector_type(8)));
typedef __bf16 bf16x8 __attribute__((ext_vector_type(8)));

static __device__ __forceinline__ unsigned short f2bf(float x) {
    unsigned u = __float_as_uint(x);
    u = u + 0x7FFFu + ((u >> 16) & 1u);   // RNE
    return (unsigned short)(u >> 16);
}
static __device__ __forceinline__ float bf2f(unsigned short h) {
    return __uint_as_float(((unsigned)h) << 16);
}
static __device__ __forceinline__ bf16x8 as_bf(s16x8 v) {
    union { s16x8 s; bf16x8 b; } u; u.s = v; return u.b;
}
static __device__ __forceinline__ bf16x8 ld_bf8(const unsigned short* p) {
    return as_bf(*(const s16x8*)p);
}
// async global->LDS, 16B/lane; LDS dest = wave-uniform base + lane*16 (m104)
static __device__ __forceinline__ void gload_lds16(const void* g, void* l) {
    __builtin_amdgcn_global_load_lds(
        (const __attribute__((address_space(1))) void*)g,
        (__attribute__((address_space(3))) void*)l,
        16, 0, 0);
}

__global__ __launch_bounds__(256) void fill_f32(
    float* __restrict__ out, float v, int n)
{
    int i = blockIdx.x * 256 + threadIdx.x;
    if (i < n) out[i] = v;
}

// ---------------- fp32 -> bf16 convert (8 elems/thread) ----------------
__global__ __launch_bounds__(256) void convert_f32_bf16(
    const float* __restrict__ in, unsigned short* __restrict__ out)
{
    long i = ((long)blockIdx.x * 256 + threadIdx.x) * 8;
    f32x4 a = *(const f32x4*)&in[i];
    f32x4 b = *(const f32x4*)&in[i + 4];
    s16x8 o;
#pragma unroll
    for (int e = 0; e < 4; ++e) {
        o[e]     = (short)f2bf(a[e]);
        o[e + 4] = (short)f2bf(b[e]);
    }
    *(s16x8*)&out[i] = o;
}

// ------- batched W[k][n] fp32 -> Wt[n][k] bf16 (4 matrices, z selects) ----
__global__ __launch_bounds__(256) void transpose_w4(
    const float* __restrict__ Wq, const float* __restrict__ Wk,
    const float* __restrict__ Wv, const float* __restrict__ Wo,
    unsigned short* __restrict__ wqkvT, unsigned short* __restrict__ woT)
{
    __shared__ float t[32][33];
    const int z = blockIdx.z;
    const float* W = (z == 0) ? Wq : (z == 1) ? Wk : (z == 2) ? Wv : Wo;
    unsigned short* Wt = (z < 3) ? (wqkvT + (long)z * HID * HID) : woT;
    int k0 = blockIdx.x * 32, n0 = blockIdx.y * 32;
    int tx = threadIdx.x & 31, ty = threadIdx.x >> 5;
#pragma unroll
    for (int r = ty; r < 32; r += 8)
        t[r][tx] = W[(long)(k0 + r) * HID + n0 + tx];
    __syncthreads();
#pragma unroll
    for (int r = ty; r < 32; r += 8)
        Wt[(long)(n0 + r) * HID + k0 + tx] = f2bf(t[tx][r]);
}

// ======== 256x(NF*64) single-phase GEMM, fat-wave: wave-tile 128 x NF*16 ====
// dbuf LDS; counted vmcnt(4+NF); setprio; 2-D XCD chunking; write-combined
// epilogue. ROPE=true (QKV): rope fused into epilogue via LDS pair-exchange.
template<int NF, bool F32OUT, bool ROPE>
__global__ __launch_bounds__(512, 2) void gemm_8phase(
    const unsigned short* __restrict__ A,    // [M][K] bf16
    const unsigned short* __restrict__ Bt,   // [N][K] bf16
    const float* __restrict__ bq, const float* __restrict__ bk,
    const float* __restrict__ bv,
    unsigned short* __restrict__ Cb, float* __restrict__ Cf,
    int K, int ldc, int nbn, int sm, int sn, int hasBias)
{
    constexpr int BUFE = 16384 + NF * 4096;      // elems per LDS buffer (A|B)
    __shared__ unsigned short lds[2 * BUFE];
    const int tid = threadIdx.x;
    const int wid = tid >> 6, lane = tid & 63;
    const int l16 = lane & 15, l4 = lane >> 4;
    const int wm = wid >> 2, wn = wid & 3;

    // 2-D XCD chunk decode: 8 chunks of sm x sn tiles
    const int bid = blockIdx.x;
    const int xcd = bid & 7, idx = bid >> 3;
    const int ncn = nbn / sn;                    // chunk-cols
    const int cm = xcd / ncn, cn = xcd % ncn;
    const int lm = idx / sn,  ln = idx % sn;
    const long bm = (long)(cm * sm + lm) * 256;
    const long bn = (long)(cn * sn + ln) * (NF * 64);

    const int NT = K >> 6;
    const long strideB = (long)K * 2;            // bytes per global row
    const int srow = tid >> 3;                   // 0..63 row within 64-row chunk
    const int scb  = ((tid & 7) * 16) ^ ((srow & 7) << 4);   // pre-swizzled src byte

    auto stageA = [&](int t, int c) {            // c in 0..3
        unsigned short* base = &lds[(t & 1) * BUFE];
        const int row = c * 64 + srow;
        const char* src = (const char*)A + (bm + row) * strideB + (long)t * 128 + scb;
        gload_lds16(src, base + (c * 64 + wid * 8) * 64);
    };
    auto stageB = [&](int t, int c) {            // c in 0..NF-1
        unsigned short* base = &lds[(t & 1) * BUFE + 16384];
        const int row = c * 64 + srow;
        const char* src = (const char*)Bt + (bn + row) * strideB + (long)t * 128 + scb;
        gload_lds16(src, base + (c * 64 + wid * 8) * 64);
    };

    f32x4 acc[8][NF];
#pragma unroll
    for (int i = 0; i < 8; ++i)
#pragma unroll
        for (int j = 0; j < NF; ++j) acc[i][j] = f32x4{0.f, 0.f, 0.f, 0.f};

    // compute one K-tile: kk-outer so only one kk's fragments are live at once
    auto compute = [&](const unsigned short* Ab, const unsigned short* Bb) {
#pragma unroll
        for (int kk = 0; kk < 2; ++kk) {
            bf16x8 bfr[NF];
#pragma unroll
            for (int j = 0; j < NF; ++j) {
                const int row = wn * (NF * 16) + j * 16 + l16;
                const char* rb = (const char*)Bb + row * 128;
                bfr[j] = as_bf(*(const s16x8*)(rb + ((kk * 64 + l4 * 16) ^ ((l16 & 7) << 4))));
            }
#pragma unroll
            for (int half = 0; half < 2; ++half) {
                bf16x8 af[4];
#pragma unroll
                for (int i = 0; i < 4; ++i) {
                    const int row = wm * 128 + (half * 4 + i) * 16 + l16;
                    const char* rb = (const char*)Ab + row * 128;
                    af[i] = as_bf(*(const s16x8*)(rb + ((kk * 64 + l4 * 16) ^ ((l16 & 7) << 4))));
                }
                __builtin_amdgcn_s_setprio(1);
#pragma unroll
                for (int i = 0; i < 4; ++i)
#pragma unroll
                    for (int j = 0; j < NF; ++j)
                        acc[half * 4 + i][j] = __builtin_amdgcn_mfma_f32_16x16x32_bf16(
                            af[i], bfr[j], acc[half * 4 + i][j], 0, 0, 0);
                __builtin_amdgcn_s_setprio(0);
            }
        }
    };

    // prologue: stage tile 0 fully (4+NF loads/thread)
#pragma unroll
    for (int c = 0; c < 4; ++c) stageA(0, c);
#pragma unroll
    for (int c = 0; c < NF; ++c) stageB(0, c);

    for (int t = 0; t < NT - 1; ++t) {
        const unsigned short* Ab = &lds[(t & 1) * BUFE];
        const unsigned short* Bb = Ab + 16384;
#pragma unroll
        for (int c = 0; c < 4; ++c) stageA(t + 1, c);
#pragma unroll
        for (int c = 0; c < NF; ++c) stageB(t + 1, c);
        __builtin_amdgcn_sched_barrier(0);
        // counted wait: tile t's (4+NF) loads done, tile t+1's in flight
        if constexpr (NF == 6)      asm volatile("s_waitcnt vmcnt(10)" ::: "memory");
        else if constexpr (NF == 3) asm volatile("s_waitcnt vmcnt(7)" ::: "memory");
        else                        asm volatile("s_waitcnt vmcnt(6)" ::: "memory");
        __builtin_amdgcn_s_barrier();
        __builtin_amdgcn_sched_barrier(0);                 // no ds_read above validity
        compute(Ab, Bb);
        __builtin_amdgcn_s_barrier();   // all reads of buf done before t+2 staging
    }
    {
        const unsigned short* Ab = &lds[((NT - 1) & 1) * BUFE];
        const unsigned short* Bb = Ab + 16384;
        asm volatile("s_waitcnt vmcnt(0)" ::: "memory");
        __builtin_amdgcn_s_barrier();
        __builtin_amdgcn_sched_barrier(0);
        compute(Ab, Bb);
    }

    // bias per owned column
    float bvv[NF];
#pragma unroll
    for (int nf = 0; nf < NF; ++nf) {
        const long n = bn + wn * (NF * 16) + nf * 16 + l16;
        bvv[nf] = 0.f;
        if (hasBias)
            bvv[nf] = (n < HID) ? bq[n] : ((n < 2 * HID) ? bk[n - HID] : bv[n - 2 * HID]);
    }

    if constexpr (ROPE) {
        // fused RoPE epilogue: 4 row-chunks of 64; acc+bias -> LDS fp32 [64][385];
        // pairs (j, j+64) rotated in fp32; Q scaled by (1/sqrt(128))*log2(e);
        // V heads pass through. Coalesced bf16 stores.
        constexpr int NH = NF / 2;               // whole heads per block (3 for NF=6)
        float* fl = (float*)lds;                 // reuse staging LDS (64*385*4 B)
        const int jr = tid & 63;
        const int rquo = tid >> 6;               // 0..7
        const float inv = exp2f(-(float)jr * 0.20762050593046f);  // 10000^(-j/64)
#pragma unroll
        for (int c = 0; c < 4; ++c) {
            __builtin_amdgcn_s_barrier();        // prior chunk reads / final compute done
            if (wm == (c >> 1)) {
                const int mf0 = (c & 1) * 4;
#pragma unroll
                for (int mfi = 0; mfi < 4; ++mfi)
#pragma unroll
                    for (int r = 0; r < 4; ++r) {
                        const int rl = mfi * 16 + l4 * 4 + r;
#pragma unroll
                        for (int nf = 0; nf < NF; ++nf)
                            fl[rl * 385 + wn * (NF * 16) + nf * 16 + l16] =
                                acc[mf0 + mfi][nf][r] + bvv[nf];
                    }
            }
            __builtin_amdgcn_s_barrier();
#pragma unroll
            for (int rr = 0; rr < 8; ++rr) {
                const int rl = rr * 8 + rquo;
                const long m = bm + (c >> 1) * 128 + (c & 1) * 64 + rl;
                const int s = (int)(m & (SEQ - 1));
                float sn, cs;
                sincosf((float)s * inv, &sn, &cs);
#pragma unroll
                for (int hh = 0; hh < NH; ++hh) {
                    const long n = bn + hh * 128 + jr;
                    const bool ron = n < 2 * HID;          // rope Q,K; V passthrough
                    const float qsv = (n < HID) ? 0.12751744581845f : 1.0f;
                    const float se = ron ? sn : 0.f;
                    const float ce = ron ? cs : 1.f;
                    const float x1 = fl[rl * 385 + hh * 128 + jr];
                    const float x2 = fl[rl * 385 + hh * 128 + jr + 64];
                    Cb[m * (long)ldc + n]      = f2bf((x1 * ce - x2 * se) * qsv);
                    Cb[m * (long)ldc + n + 64] = f2bf((x2 * ce + x1 * se) * qsv);
                }
            }
        }
    } else {
        // plain epilogue: row-outer / nf-inner (write combining)
#pragma unroll
        for (int mf = 0; mf < 8; ++mf) {
#pragma unroll
            for (int r = 0; r < 4; ++r) {
                const long m = bm + wm * 128 + mf * 16 + l4 * 4 + r;
#pragma unroll
                for (int nf = 0; nf < NF; ++nf) {
                    const long n = bn + wn * (NF * 16) + nf * 16 + l16;
                    float v = acc[mf][nf][r] + bvv[nf];
                    if (F32OUT) Cf[m * (long)ldc + n] = v;
                    else        Cb[m * (long)ldc + n] = f2bf(v);
                }
            }
        }
    }
}

// ---------------- V[b,s,h,d] -> VT[b,h,d,s] ----------------
__global__ __launch_bounds__(256) void v_transpose(
    const unsigned short* __restrict__ qkv, unsigned short* __restrict__ vt)
{
    __shared__ unsigned short t[32][33];
    int bh = blockIdx.z;
    int b = bh >> 4, h = bh & 15;
    int s0 = blockIdx.x * 32, d0 = blockIdx.y * 32;
    int tx = threadIdx.x & 31, ty = threadIdx.x >> 5;
#pragma unroll
    for (int r = ty; r < 32; r += 8)
        t[r][tx] = qkv[(long)(b * SEQ + s0 + r) * QKN + 2 * HID + h * HD + d0 + tx];
    __syncthreads();
#pragma unroll
    for (int r = ty; r < 32; r += 8)
        vt[((long)bh * HD + d0 + r) * SEQ + s0 + tx] = t[tx][r];
}

// -------- MFMA flash attention (r19 best-known): 8 waves / QBLK=128, T2
// swizzles, dbuf staging, defer-max, swapped-QK^T in-register softmax,
// log2-domain exp2, max3 tree. XCD-chunked. (T5 setprio reverted: LDS-issue-
// bound kernel, priority hints regressed it 127.6->129.6 in r20.)
__global__ __launch_bounds__(512) void attn_kernel(
    const unsigned short* __restrict__ qkv,
    const unsigned short* __restrict__ vt,
    unsigned short* __restrict__ attnout)
{
    __shared__ unsigned short Ks[2][64 * 128];   // [kv][d], byte ^= (kv&7)<<4
    __shared__ unsigned short Vs[2][128 * 64];   // [d][kv], byte ^= (d&7)<<4

    const int tid = threadIdx.x, wid = tid >> 6, lane = tid & 63;
    const int l16 = lane & 15, l4 = lane >> 4;
    const int bid = blockIdx.x;                  // 0..511
    const int xcd = bid & 7, idx = bid >> 3;     // idx 0..63
    const int bh = xcd * 4 + (idx >> 4);         // 4 heads per XCD
    const int qt = idx & 15;                     // 16 q-tiles (QBLK=128)
    const int b = bh >> 4, h = bh & 15;
    const long rowbase = (long)b * SEQ;

    const unsigned short* Kg = &qkv[rowbase * QKN + HID + h * HD];  // + s*QKN
    const unsigned short* Vg = &vt[(long)bh * HD * SEQ];            // + d*SEQ

    // 16 K chunks + 16 V chunks over 8 waves -> 2+2 per wave
    auto stage = [&](int buf, int kv0) {
#pragma unroll
        for (int i = 0; i < 2; ++i) {
            int c = wid * 2 + i;
            int kr = c * 4 + l4;
            int kcb = (l16 * 16) ^ ((kr & 7) << 4);
            gload_lds16((const char*)(Kg + (long)(kv0 + kr) * QKN) + kcb, &Ks[buf][c * 512]);
            int vr = c * 8 + (lane >> 3);
            int vcb = ((lane & 7) * 16) ^ ((vr & 7) << 4);
            gload_lds16((const char*)(Vg + (long)vr * SEQ + kv0) + vcb, &Vs[buf][c * 512]);
        }
    };

    bf16x8 qf[4];
    {
        const long qrow = rowbase + qt * 128 + wid * 16 + l16;
        const unsigned short* qp = &qkv[qrow * QKN + h * HD];
#pragma unroll
        for (int kc = 0; kc < 4; ++kc) qf[kc] = ld_bf8(qp + kc * 32 + l4 * 8);
    }

    f32x4 o[8];
#pragma unroll
    for (int nb = 0; nb < 8; ++nb) o[nb] = f32x4{0.f, 0.f, 0.f, 0.f};
    float mrun = -3.0e38f, lrun = 0.f;       // per-lane scalars (q = l16), log2 units

    const int srcA = ((l4 & 1) * 2) * 16 + l16;   // lane of l4_s = 2(l4&1)
    const int srcB = srcA + 16;                   // lane of l4_s = 2(l4&1)+1
    const bool sel = (l4 >> 1) != 0;              // nf_s = 2kc + (l4>>1)

    stage(0, 0);
    __syncthreads();

    for (int t = 0; t < SEQ / 64; ++t) {
        const int cur = t & 1;
        if (t < SEQ / 64 - 1) stage(cur ^ 1, (t + 1) * 64);
        __builtin_amdgcn_sched_barrier(0);   // pin: issue next-tile stage first

        const unsigned short* Kc = &Ks[cur][0];
        const unsigned short* Vc = &Vs[cur][0];

        // S^T = K Q^T (log2 domain): A = kf (rows=kv), B = qf (cols=q)
        f32x4 sc[4];
#pragma unroll
        for (int nf = 0; nf < 4; ++nf) sc[nf] = f32x4{0.f, 0.f, 0.f, 0.f};
#pragma unroll
        for (int kc = 0; kc < 4; ++kc) {
#pragma unroll
            for (int nf = 0; nf < 4; ++nf) {
                int row = nf * 16 + l16;
                int cb = (kc * 64 + l4 * 16) ^ ((row & 7) << 4);
                bf16x8 kf = as_bf(*(const s16x8*)((const char*)Kc + row * 256 + cb));
                sc[nf] = __builtin_amdgcn_mfma_f32_16x16x32_bf16(kf, qf[kc], sc[nf], 0, 0, 0);
            }
        }

        // per-lane max over 16 values via max3 tree, then combine 4 l4-copies
        float m0 = fmaxf(fmaxf(sc[0][0], sc[0][1]), sc[0][2]);
        float m1 = fmaxf(fmaxf(sc[0][3], sc[1][0]), sc[1][1]);
        float m2 = fmaxf(fmaxf(sc[1][2], sc[1][3]), sc[2][0]);
        float m3 = fmaxf(fmaxf(sc[2][1], sc[2][2]), sc[2][3]);
        float m4 = fmaxf(fmaxf(sc[3][0], sc[3][1]), sc[3][2]);
        float tmax = fmaxf(fmaxf(m0, m1), m2);
        tmax = fmaxf(fmaxf(m3, m4), tmax);
        tmax = fmaxf(tmax, sc[3][3]);
        tmax = fmaxf(tmax, __shfl_xor(tmax, 16, 64));
        tmax = fmaxf(tmax, __shfl_xor(tmax, 32, 64));

        // defer-max (T13, log2 units): skip rescale when growth <= 8
        if (!__all(tmax - mrun <= 8.0f)) {
            float mn = fmaxf(mrun, tmax);
            float sc_ = exp2f(mrun - mn);
            mrun = mn;
            lrun *= sc_;
            float s_[4];
#pragma unroll
            for (int r = 0; r < 4; ++r) s_[r] = __shfl(sc_, l4 * 4 + r, 64);
#pragma unroll
            for (int nb = 0; nb < 8; ++nb)
#pragma unroll
                for (int r = 0; r < 4; ++r) o[nb][r] *= s_[r];
        }

        // P = exp2(S - m); pack to bf16 pairs; sum
        unsigned pk[4][2];
        float sum = 0.f;
#pragma unroll
        for (int nf = 0; nf < 4; ++nf) {
            float p0 = exp2f(sc[nf][0] - mrun);
            float p1 = exp2f(sc[nf][1] - mrun);
            float p2 = exp2f(sc[nf][2] - mrun);
            float p3 = exp2f(sc[nf][3] - mrun);
            sum += (p0 + p1) + (p2 + p3);
            union { __bf16 b[2]; unsigned u; } w0, w1;
            w0.b[0] = (__bf16)p0; w0.b[1] = (__bf16)p1;
            w1.b[0] = (__bf16)p2; w1.b[1] = (__bf16)p3;
            pk[nf][0] = w0.u; pk[nf][1] = w1.u;
        }
        sum += __shfl_xor(sum, 16, 64);
        sum += __shfl_xor(sum, 32, 64);
        lrun += sum;

        // redistribute P into PV A-fragments (4-lane group exchange)
        union { unsigned u[4]; bf16x8 v; } pa0, pa1;
#pragma unroll
        for (int w = 0; w < 2; ++w) {
            unsigned a0 = __shfl(pk[0][w], srcA, 64);
            unsigned a1 = __shfl(pk[1][w], srcA, 64);
            unsigned b0 = __shfl(pk[0][w], srcB, 64);
            unsigned b1 = __shfl(pk[1][w], srcB, 64);
            pa0.u[w]     = sel ? a1 : a0;
            pa0.u[2 + w] = sel ? b1 : b0;
            unsigned c0 = __shfl(pk[2][w], srcA, 64);
            unsigned c1 = __shfl(pk[3][w], srcA, 64);
            unsigned d0 = __shfl(pk[2][w], srcB, 64);
            unsigned d1 = __shfl(pk[3][w], srcB, 64);
            pa1.u[w]     = sel ? c1 : c0;
            pa1.u[2 + w] = sel ? d1 : d0;
        }

        // O += P V   (A = pa (q rows), B = V^T [d][kv] swizzled)
#pragma unroll
        for (int kc = 0; kc < 2; ++kc) {
            bf16x8 pav = kc ? pa1.v : pa0.v;
#pragma unroll
            for (int nb = 0; nb < 8; ++nb) {
                int vrow = nb * 16 + l16;
                int vcb = (kc * 64 + l4 * 16) ^ ((vrow & 7) << 4);
                bf16x8 vb = as_bf(*(const s16x8*)((const char*)Vc + vrow * 128 + vcb));
                o[nb] = __builtin_amdgcn_mfma_f32_16x16x32_bf16(pav, vb, o[nb], 0, 0, 0);
            }
        }
        __syncthreads();   // implicit vmcnt(0): next-tile stage (issued pre-compute) done
    }

    // stats live at q=l16 lanes; o rows are q=l4*4+r -> hop via 4 shuffles
    float linv = 1.f / lrun;
    float li[4];
#pragma unroll
    for (int r = 0; r < 4; ++r) li[r] = __shfl(linv, l4 * 4 + r, 64);
#pragma unroll
    for (int r = 0; r < 4; ++r) {
        long m = rowbase + qt * 128 + wid * 16 + l4 * 4 + r;
#pragma unroll
        for (int nb = 0; nb < 8; ++nb)
            attnout[m * HID + h * HD + nb * 16 + l16] = f2bf(o[nb][r] * li[r]);
    }
}

// ---------------- launch ----------------
extern "C" void kernel_launch(void* const* d_in, const int* in_sizes, int n_in,
                              void* d_out, int out_size, void* d_ws, size_t ws_size,
                              hipStream_t stream)
{
    const float* hs = (const float*)d_in[0];
    const float* Wq = (const float*)d_in[1];
    const float* bq = (const float*)d_in[2];
    const float* Wk = (const float*)d_in[3];
    const float* bk = (const float*)d_in[4];
    const float* Wv = (const float*)d_in[5];
    const float* bv = (const float*)d_in[6];
    const float* Wo = (const float*)d_in[7];
    float* out = (float*)d_out;   // fp32 output (confirmed round 5)

    bool shapes_ok =
        (n_in == 8) && (out_size == 8388608) &&
        in_sizes[0] == 8388608 && in_sizes[1] == 4194304 && in_sizes[2] == 2048 &&
        in_sizes[3] == 4194304 && in_sizes[4] == 2048 && in_sizes[5] == 4194304 &&
        in_sizes[6] == 2048 && in_sizes[7] == 4194304;
    if (!shapes_ok || ws_size < 117440512ull) {
        fill_f32<<<32768, 256, 0, stream>>>(out, shapes_ok ? 1000.f : 0.f, out_size);
        return;
    }

    char* ws = (char*)d_ws;
    unsigned short* hsB     = (unsigned short*)(ws);              // [4096][2048] bf16
    unsigned short* qkvB    = (unsigned short*)(ws + 16777216);   // [4096][6144] bf16
    unsigned short* wqkvT   = (unsigned short*)(ws + 67108864);   // [6144][2048] bf16
    unsigned short* vtB     = (unsigned short*)(ws + 92274688);   // [32][128][2048] bf16
    unsigned short* woT     = (unsigned short*)(ws + 109051904);  // [2048][2048] bf16
    unsigned short* attnout = hsB;   // hsB dead after QKV GEMM

    convert_f32_bf16<<<4096, 256, 0, stream>>>(hs, hsB);
    transpose_w4<<<dim3(64, 64, 4), 256, 0, stream>>>(Wq, Wk, Wv, Wo, wqkvT, woT);

    // QKV fat-wave + fused RoPE epilogue: 256x384 tiles -> 256 blocks = 1 round
    gemm_8phase<6, false, true><<<dim3(256), 512, 0, stream>>>(
        hsB, wqkvT, bq, bk, bv, qkvB, nullptr, 2048, QKN, 16, 8, 4, 1);
    v_transpose<<<dim3(64, 4, 32), 256, 0, stream>>>(qkvB, vtB);
    // attn: QBLK=128, 8 waves, 512 blocks, XCD-chunked (4 heads x 16 qt per XCD)
    attn_kernel<<<dim3(512), 512, 0, stream>>>(qkvB, vtB, attnout);
    // out-proj: 256x128 tiles, 16x16 grid, XCD chunks 4x8, fp32 out
    gemm_8phase<2, true, false><<<dim3(256), 512, 0, stream>>>(
        attnout, woT, nullptr, nullptr, nullptr, nullptr, out, 2048, HID, 16, 4, 8, 0);
}

// Round 22
// 284.583 us; speedup vs baseline: 1.1049x; 1.0307x over previous
//
#include <hip/hip_runtime.h>

#define HID 2048
#define SEQ 2048
#define HD 128
#define QKN 6144      // 3*HID

typedef float f32x4 __attribute__((ext_vector_type(4)));
typedef float f32x16 __attribute__((ext_vector_type(16)));
typedef short s16x8 __attribute__((ext_vector_type(8)));
typedef __bf16 bf16x8 __attribute__((ext_vector_type(8)));

static __device__ __forceinline__ unsigned short f2bf(float x) {
    unsigned u = __float_as_uint(x);
    u = u + 0x7FFFu + ((u >> 16) & 1u);   // RNE
    return (unsigned short)(u >> 16);
}
static __device__ __forceinline__ float bf2f(unsigned short h) {
    return __uint_as_float(((unsigned)h) << 16);
}
static __device__ __forceinline__ bf16x8 as_bf(s16x8 v) {
    union { s16x8 s; bf16x8 b; } u; u.s = v; return u.b;
}
static __device__ __forceinline__ bf16x8 ld_bf8(const unsigned short* p) {
    return as_bf(*(const s16x8*)p);
}
// async global->LDS, 16B/lane; LDS dest = wave-uniform base + lane*16 (m104)
static __device__ __forceinline__ void gload_lds16(const void* g, void* l) {
    __builtin_amdgcn_global_load_lds(
        (const __attribute__((address_space(1))) void*)g,
        (__attribute__((address_space(3))) void*)l,
        16, 0, 0);
}

__global__ __launch_bounds__(256) void fill_f32(
    float* __restrict__ out, float v, int n)
{
    int i = blockIdx.x * 256 + threadIdx.x;
    if (i < n) out[i] = v;
}

// ---------------- fp32 -> bf16 convert (8 elems/thread) ----------------
__global__ __launch_bounds__(256) void convert_f32_bf16(
    const float* __restrict__ in, unsigned short* __restrict__ out)
{
    long i = ((long)blockIdx.x * 256 + threadIdx.x) * 8;
    f32x4 a = *(const f32x4*)&in[i];
    f32x4 b = *(const f32x4*)&in[i + 4];
    s16x8 o;
#pragma unroll
    for (int e = 0; e < 4; ++e) {
        o[e]     = (short)f2bf(a[e]);
        o[e + 4] = (short)f2bf(b[e]);
    }
    *(s16x8*)&out[i] = o;
}

// ------- batched W[k][n] fp32 -> Wt[n][k] bf16 (4 matrices, z selects) ----
__global__ __launch_bounds__(256) void transpose_w4(
    const float* __restrict__ Wq, const float* __restrict__ Wk,
    const float* __restrict__ Wv, const float* __restrict__ Wo,
    unsigned short* __restrict__ wqkvT, unsigned short* __restrict__ woT)
{
    __shared__ float t[32][33];
    const int z = blockIdx.z;
    const float* W = (z == 0) ? Wq : (z == 1) ? Wk : (z == 2) ? Wv : Wo;
    unsigned short* Wt = (z < 3) ? (wqkvT + (long)z * HID * HID) : woT;
    int k0 = blockIdx.x * 32, n0 = blockIdx.y * 32;
    int tx = threadIdx.x & 31, ty = threadIdx.x >> 5;
#pragma unroll
    for (int r = ty; r < 32; r += 8)
        t[r][tx] = W[(long)(k0 + r) * HID + n0 + tx];
    __syncthreads();
#pragma unroll
    for (int r = ty; r < 32; r += 8)
        Wt[(long)(n0 + r) * HID + k0 + tx] = f2bf(t[tx][r]);
}

// ======== 256x(NF*64) single-phase GEMM, fat-wave: wave-tile 128 x NF*16 ====
// dbuf LDS; counted vmcnt(4+NF); setprio; 2-D XCD chunking; write-combined
// epilogue. ROPE=true (QKV): rope fused into epilogue via LDS pair-exchange.
template<int NF, bool F32OUT, bool ROPE>
__global__ __launch_bounds__(512, 2) void gemm_8phase(
    const unsigned short* __restrict__ A,    // [M][K] bf16
    const unsigned short* __restrict__ Bt,   // [N][K] bf16
    const float* __restrict__ bq, const float* __restrict__ bk,
    const float* __restrict__ bv,
    unsigned short* __restrict__ Cb, float* __restrict__ Cf,
    int K, int ldc, int nbn, int sm, int sn, int hasBias)
{
    constexpr int BUFE = 16384 + NF * 4096;      // elems per LDS buffer (A|B)
    __shared__ unsigned short lds[2 * BUFE];
    const int tid = threadIdx.x;
    const int wid = tid >> 6, lane = tid & 63;
    const int l16 = lane & 15, l4 = lane >> 4;
    const int wm = wid >> 2, wn = wid & 3;

    // 2-D XCD chunk decode: 8 chunks of sm x sn tiles
    const int bid = blockIdx.x;
    const int xcd = bid & 7, idx = bid >> 3;
    const int ncn = nbn / sn;                    // chunk-cols
    const int cm = xcd / ncn, cn = xcd % ncn;
    const int lm = idx / sn,  ln = idx % sn;
    const long bm = (long)(cm * sm + lm) * 256;
    const long bn = (long)(cn * sn + ln) * (NF * 64);

    const int NT = K >> 6;
    const long strideB = (long)K * 2;            // bytes per global row
    const int srow = tid >> 3;                   // 0..63 row within 64-row chunk
    const int scb  = ((tid & 7) * 16) ^ ((srow & 7) << 4);   // pre-swizzled src byte

    auto stageA = [&](int t, int c) {            // c in 0..3
        unsigned short* base = &lds[(t & 1) * BUFE];
        const int row = c * 64 + srow;
        const char* src = (const char*)A + (bm + row) * strideB + (long)t * 128 + scb;
        gload_lds16(src, base + (c * 64 + wid * 8) * 64);
    };
    auto stageB = [&](int t, int c) {            // c in 0..NF-1
        unsigned short* base = &lds[(t & 1) * BUFE + 16384];
        const int row = c * 64 + srow;
        const char* src = (const char*)Bt + (bn + row) * strideB + (long)t * 128 + scb;
        gload_lds16(src, base + (c * 64 + wid * 8) * 64);
    };

    f32x4 acc[8][NF];
#pragma unroll
    for (int i = 0; i < 8; ++i)
#pragma unroll
        for (int j = 0; j < NF; ++j) acc[i][j] = f32x4{0.f, 0.f, 0.f, 0.f};

    // compute one K-tile: kk-outer so only one kk's fragments are live at once
    auto compute = [&](const unsigned short* Ab, const unsigned short* Bb) {
#pragma unroll
        for (int kk = 0; kk < 2; ++kk) {
            bf16x8 bfr[NF];
#pragma unroll
            for (int j = 0; j < NF; ++j) {
                const int row = wn * (NF * 16) + j * 16 + l16;
                const char* rb = (const char*)Bb + row * 128;
                bfr[j] = as_bf(*(const s16x8*)(rb + ((kk * 64 + l4 * 16) ^ ((l16 & 7) << 4))));
            }
#pragma unroll
            for (int half = 0; half < 2; ++half) {
                bf16x8 af[4];
#pragma unroll
                for (int i = 0; i < 4; ++i) {
                    const int row = wm * 128 + (half * 4 + i) * 16 + l16;
                    const char* rb = (const char*)Ab + row * 128;
                    af[i] = as_bf(*(const s16x8*)(rb + ((kk * 64 + l4 * 16) ^ ((l16 & 7) << 4))));
                }
                __builtin_amdgcn_s_setprio(1);
#pragma unroll
                for (int i = 0; i < 4; ++i)
#pragma unroll
                    for (int j = 0; j < NF; ++j)
                        acc[half * 4 + i][j] = __builtin_amdgcn_mfma_f32_16x16x32_bf16(
                            af[i], bfr[j], acc[half * 4 + i][j], 0, 0, 0);
                __builtin_amdgcn_s_setprio(0);
            }
        }
    };

    // prologue: stage tile 0 fully (4+NF loads/thread)
#pragma unroll
    for (int c = 0; c < 4; ++c) stageA(0, c);
#pragma unroll
    for (int c = 0; c < NF; ++c) stageB(0, c);

    for (int t = 0; t < NT - 1; ++t) {
        const unsigned short* Ab = &lds[(t & 1) * BUFE];
        const unsigned short* Bb = Ab + 16384;
#pragma unroll
        for (int c = 0; c < 4; ++c) stageA(t + 1, c);
#pragma unroll
        for (int c = 0; c < NF; ++c) stageB(t + 1, c);
        __builtin_amdgcn_sched_barrier(0);
        // counted wait: tile t's (4+NF) loads done, tile t+1's in flight
        if constexpr (NF == 6)      asm volatile("s_waitcnt vmcnt(10)" ::: "memory");
        else if constexpr (NF == 3) asm volatile("s_waitcnt vmcnt(7)" ::: "memory");
        else                        asm volatile("s_waitcnt vmcnt(6)" ::: "memory");
        __builtin_amdgcn_s_barrier();
        __builtin_amdgcn_sched_barrier(0);                 // no ds_read above validity
        compute(Ab, Bb);
        __builtin_amdgcn_s_barrier();   // all reads of buf done before t+2 staging
    }
    {
        const unsigned short* Ab = &lds[((NT - 1) & 1) * BUFE];
        const unsigned short* Bb = Ab + 16384;
        asm volatile("s_waitcnt vmcnt(0)" ::: "memory");
        __builtin_amdgcn_s_barrier();
        __builtin_amdgcn_sched_barrier(0);
        compute(Ab, Bb);
    }

    // bias per owned column
    float bvv[NF];
#pragma unroll
    for (int nf = 0; nf < NF; ++nf) {
        const long n = bn + wn * (NF * 16) + nf * 16 + l16;
        bvv[nf] = 0.f;
        if (hasBias)
            bvv[nf] = (n < HID) ? bq[n] : ((n < 2 * HID) ? bk[n - HID] : bv[n - 2 * HID]);
    }

    if constexpr (ROPE) {
        // fused RoPE epilogue: 4 row-chunks of 64; acc+bias -> LDS fp32 [64][385];
        // pairs (j, j+64) rotated in fp32; Q scaled by (1/sqrt(128))*log2(e);
        // V heads pass through. Coalesced bf16 stores.
        constexpr int NH = NF / 2;               // whole heads per block (3 for NF=6)
        float* fl = (float*)lds;                 // reuse staging LDS (64*385*4 B)
        const int jr = tid & 63;
        const int rquo = tid >> 6;               // 0..7
        const float inv = exp2f(-(float)jr * 0.20762050593046f);  // 10000^(-j/64)
#pragma unroll
        for (int c = 0; c < 4; ++c) {
            __builtin_amdgcn_s_barrier();        // prior chunk reads / final compute done
            if (wm == (c >> 1)) {
                const int mf0 = (c & 1) * 4;
#pragma unroll
                for (int mfi = 0; mfi < 4; ++mfi)
#pragma unroll
                    for (int r = 0; r < 4; ++r) {
                        const int rl = mfi * 16 + l4 * 4 + r;
#pragma unroll
                        for (int nf = 0; nf < NF; ++nf)
                            fl[rl * 385 + wn * (NF * 16) + nf * 16 + l16] =
                                acc[mf0 + mfi][nf][r] + bvv[nf];
                    }
            }
            __builtin_amdgcn_s_barrier();
#pragma unroll
            for (int rr = 0; rr < 8; ++rr) {
                const int rl = rr * 8 + rquo;
                const long m = bm + (c >> 1) * 128 + (c & 1) * 64 + rl;
                const int s = (int)(m & (SEQ - 1));
                float sn, cs;
                sincosf((float)s * inv, &sn, &cs);
#pragma unroll
                for (int hh = 0; hh < NH; ++hh) {
                    const long n = bn + hh * 128 + jr;
                    const bool ron = n < 2 * HID;          // rope Q,K; V passthrough
                    const float qsv = (n < HID) ? 0.12751744581845f : 1.0f;
                    const float se = ron ? sn : 0.f;
                    const float ce = ron ? cs : 1.f;
                    const float x1 = fl[rl * 385 + hh * 128 + jr];
                    const float x2 = fl[rl * 385 + hh * 128 + jr + 64];
                    Cb[m * (long)ldc + n]      = f2bf((x1 * ce - x2 * se) * qsv);
                    Cb[m * (long)ldc + n + 64] = f2bf((x2 * ce + x1 * se) * qsv);
                }
            }
        }
    } else {
        // plain epilogue: row-outer / nf-inner (write combining)
#pragma unroll
        for (int mf = 0; mf < 8; ++mf) {
#pragma unroll
            for (int r = 0; r < 4; ++r) {
                const long m = bm + wm * 128 + mf * 16 + l4 * 4 + r;
#pragma unroll
                for (int nf = 0; nf < NF; ++nf) {
                    const long n = bn + wn * (NF * 16) + nf * 16 + l16;
                    float v = acc[mf][nf][r] + bvv[nf];
                    if (F32OUT) Cf[m * (long)ldc + n] = v;
                    else        Cb[m * (long)ldc + n] = f2bf(v);
                }
            }
        }
    }
}

// ---------------- V[b,s,h,d] -> VT[b,h,d,s] ----------------
__global__ __launch_bounds__(256) void v_transpose(
    const unsigned short* __restrict__ qkv, unsigned short* __restrict__ vt)
{
    __shared__ unsigned short t[32][33];
    int bh = blockIdx.z;
    int b = bh >> 4, h = bh & 15;
    int s0 = blockIdx.x * 32, d0 = blockIdx.y * 32;
    int tx = threadIdx.x & 31, ty = threadIdx.x >> 5;
#pragma unroll
    for (int r = ty; r < 32; r += 8)
        t[r][tx] = qkv[(long)(b * SEQ + s0 + r) * QKN + 2 * HID + h * HD + d0 + tx];
    __syncthreads();
#pragma unroll
    for (int r = ty; r < 32; r += 8)
        vt[((long)bh * HD + d0 + r) * SEQ + s0 + tx] = t[tx][r];
}

// -------- MFMA flash attention r22: 32x32x16 MFMA shape, 8 waves x 32 q
// (QBLK=256). Per-fragment LDS read serves 32 q-rows (halved traffic/q vs
// 16x16). S^T lane layout: q = lane&31 -> per-lane scalar stats, single
// shfl_xor(32) reduce. C/D map col=lane&31, row=(reg&3)+8*(reg>>2)+4*(lane>>5)
// (m74/m101); A/B operand row=lane&31, k=(lane>>5)*8+e. T2 swizzles, dbuf,
// defer-max, log2-domain. XCD-chunked: 4 heads x 8 q-tiles per XCD.
__global__ __launch_bounds__(512, 2) void attn_kernel(
    const unsigned short* __restrict__ qkv,
    const unsigned short* __restrict__ vt,
    unsigned short* __restrict__ attnout)
{
    __shared__ unsigned short Ks[2][64 * 128];   // [kv][d], byte ^= (kv&7)<<4
    __shared__ unsigned short Vs[2][128 * 64];   // [d][kv], byte ^= (d&7)<<4

    const int tid = threadIdx.x, wid = tid >> 6, lane = tid & 63;
    const int l32 = lane & 31, hh = lane >> 5;
    const int l16 = lane & 15, l4 = lane >> 4;   // staging only
    const int bid = blockIdx.x;                  // 0..255
    const int xcd = bid & 7, idx = bid >> 3;     // idx 0..31
    const int bh = xcd * 4 + (idx >> 3);         // 4 heads per XCD
    const int qt = idx & 7;                      // 8 q-tiles (QBLK=256)
    const int b = bh >> 4, h = bh & 15;
    const long rowbase = (long)b * SEQ;

    const unsigned short* Kg = &qkv[rowbase * QKN + HID + h * HD];  // + s*QKN
    const unsigned short* Vg = &vt[(long)bh * HD * SEQ];            // + d*SEQ

    // 16 K chunks + 16 V chunks over 8 waves -> 2+2 per wave (same as r21)
    auto stage = [&](int buf, int kv0) {
#pragma unroll
        for (int i = 0; i < 2; ++i) {
            int c = wid * 2 + i;
            int kr = c * 4 + l4;
            int kcb = (l16 * 16) ^ ((kr & 7) << 4);
            gload_lds16((const char*)(Kg + (long)(kv0 + kr) * QKN) + kcb, &Ks[buf][c * 512]);
            int vr = c * 8 + (lane >> 3);
            int vcb = ((lane & 7) * 16) ^ ((vr & 7) << 4);
            gload_lds16((const char*)(Vg + (long)vr * SEQ + kv0) + vcb, &Vs[buf][c * 512]);
        }
    };

    // Q as B operand: q-col = l32, k = ks*16 + hh*8 + e (8 k-steps of 16)
    bf16x8 qf[8];
    {
        const long qrow = rowbase + qt * 256 + wid * 32 + l32;
        const unsigned short* qp = &qkv[qrow * QKN + h * HD];
#pragma unroll
        for (int ks = 0; ks < 8; ++ks)
            qf[ks] = ld_bf8(qp + ks * 16 + hh * 8);
    }

    f32x16 ob[4];
#pragma unroll
    for (int db = 0; db < 4; ++db)
#pragma unroll
        for (int r = 0; r < 16; ++r) ob[db][r] = 0.f;
    float mrun = -3.0e38f, lrun = 0.f;       // per-lane scalars (q = l32), log2 units

    stage(0, 0);
    __syncthreads();

    for (int t = 0; t < SEQ / 64; ++t) {
        const int cur = t & 1;
        if (t < SEQ / 64 - 1) stage(cur ^ 1, (t + 1) * 64);
        __builtin_amdgcn_sched_barrier(0);   // pin: issue next-tile stage first

        const unsigned short* Kc = &Ks[cur][0];
        const unsigned short* Vc = &Vs[cur][0];

        // S^T = K Q^T (log2 domain): 2 kv-blocks of 32, K=128 in 8 steps
        f32x16 sc[2];
#pragma unroll
        for (int kb = 0; kb < 2; ++kb)
#pragma unroll
            for (int r = 0; r < 16; ++r) sc[kb][r] = 0.f;
#pragma unroll
        for (int ks = 0; ks < 8; ++ks) {
#pragma unroll
            for (int kb = 0; kb < 2; ++kb) {
                int row = kb * 32 + l32;
                int cb = (ks * 32 + hh * 16) ^ ((row & 7) << 4);
                bf16x8 kf = as_bf(*(const s16x8*)((const char*)Kc + row * 256 + cb));
                sc[kb] = __builtin_amdgcn_mfma_f32_32x32x16_bf16(kf, qf[ks], sc[kb], 0, 0, 0);
            }
        }

        // per-lane max over 32 values, then combine lane pair (l, l^32)
        float tmax = sc[0][0];
#pragma unroll
        for (int kb = 0; kb < 2; ++kb)
#pragma unroll
            for (int r = 0; r < 16; ++r) tmax = fmaxf(tmax, sc[kb][r]);
        tmax = fmaxf(tmax, __shfl_xor(tmax, 32, 64));

        // defer-max (T13, log2 units): skip rescale when growth <= 8
        if (!__all(tmax - mrun <= 8.0f)) {
            float mn = fmaxf(mrun, tmax);
            float e_ = exp2f(mrun - mn);
            mrun = mn;
            lrun *= e_;
            float sr[16];
#pragma unroll
            for (int r = 0; r < 16; ++r)
                sr[r] = __shfl(e_, (r & 3) + 8 * (r >> 2) + 4 * hh, 64);
#pragma unroll
            for (int db = 0; db < 4; ++db)
#pragma unroll
                for (int r = 0; r < 16; ++r) ob[db][r] *= sr[r];
        }

        // P = exp2(S - m); pack to bf16 pairs; sum
        unsigned pk[2][8];
        float sum = 0.f;
#pragma unroll
        for (int kb = 0; kb < 2; ++kb) {
#pragma unroll
            for (int g = 0; g < 8; ++g) {
                float p0 = exp2f(sc[kb][2 * g]     - mrun);
                float p1 = exp2f(sc[kb][2 * g + 1] - mrun);
                sum += p0 + p1;
                union { __bf16 b[2]; unsigned u; } w;
                w.b[0] = (__bf16)p0; w.b[1] = (__bf16)p1;
                pk[kb][g] = w.u;
            }
        }
        sum += __shfl_xor(sum, 32, 64);
        lrun += sum;

        // PV A-fragments: pa[ks] elem e -> P[q=l32][kv = ks*16 + hh*8 + e].
        // Own regs hold kv offsets 4*hh+{0-3,8-11,16-19,24-27}; partner (l^32)
        // holds the complementary 4-blocks -> exchange packed pairs.
        union { unsigned u[4]; bf16x8 v; } pa[4];
#pragma unroll
        for (int ks = 0; ks < 4; ++ks) {
            const int kb = ks >> 1, base = (ks & 1) * 4;
            unsigned a0 = __shfl_xor(pk[kb][base + 0], 32, 64);
            unsigned a1 = __shfl_xor(pk[kb][base + 1], 32, 64);
            unsigned a2 = __shfl_xor(pk[kb][base + 2], 32, 64);
            unsigned a3 = __shfl_xor(pk[kb][base + 3], 32, 64);
            pa[ks].u[0] = hh ? a2 : pk[kb][base + 0];
            pa[ks].u[1] = hh ? a3 : pk[kb][base + 1];
            pa[ks].u[2] = hh ? pk[kb][base + 2] : a0;
            pa[ks].u[3] = hh ? pk[kb][base + 3] : a1;
        }

        // O += P V: B = V^T[d][kv] swizzled; 4 d-blocks x 4 kv-steps
#pragma unroll
        for (int ks = 0; ks < 4; ++ks) {
#pragma unroll
            for (int db = 0; db < 4; ++db) {
                int row = db * 32 + l32;
                int cb = (ks * 32 + hh * 16) ^ ((row & 7) << 4);
                bf16x8 vb = as_bf(*(const s16x8*)((const char*)Vc + row * 128 + cb));
                ob[db] = __builtin_amdgcn_mfma_f32_32x32x16_bf16(pa[ks].v, vb, ob[db], 0, 0, 0);
            }
        }
        __syncthreads();   // implicit vmcnt(0): next-tile stage (issued pre-compute) done
    }

    // stats at q=l32 lanes; ob rows are q=(r&3)+8*(r>>2)+4*hh -> hop via shuffles
    float linv = 1.f / lrun;
    float li[16];
#pragma unroll
    for (int r = 0; r < 16; ++r)
        li[r] = __shfl(linv, (r & 3) + 8 * (r >> 2) + 4 * hh, 64);
#pragma unroll
    for (int db = 0; db < 4; ++db) {
#pragma unroll
        for (int r = 0; r < 16; ++r) {
            const long m = rowbase + qt * 256 + wid * 32 + (r & 3) + 8 * (r >> 2) + 4 * hh;
            attnout[m * HID + h * HD + db * 32 + l32] = f2bf(ob[db][r] * li[r]);
        }
    }
}

// ---------------- launch ----------------
extern "C" void kernel_launch(void* const* d_in, const int* in_sizes, int n_in,
                              void* d_out, int out_size, void* d_ws, size_t ws_size,
                              hipStream_t stream)
{
    const float* hs = (const float*)d_in[0];
    const float* Wq = (const float*)d_in[1];
    const float* bq = (const float*)d_in[2];
    const float* Wk = (const float*)d_in[3];
    const float* bk = (const float*)d_in[4];
    const float* Wv = (const float*)d_in[5];
    const float* bv = (const float*)d_in[6];
    const float* Wo = (const float*)d_in[7];
    float* out = (float*)d_out;   // fp32 output (confirmed round 5)

    bool shapes_ok =
        (n_in == 8) && (out_size == 8388608) &&
        in_sizes[0] == 8388608 && in_sizes[1] == 4194304 && in_sizes[2] == 2048 &&
        in_sizes[3] == 4194304 && in_sizes[4] == 2048 && in_sizes[5] == 4194304 &&
        in_sizes[6] == 2048 && in_sizes[7] == 4194304;
    if (!shapes_ok || ws_size < 117440512ull) {
        fill_f32<<<32768, 256, 0, stream>>>(out, shapes_ok ? 1000.f : 0.f, out_size);
        return;
    }

    char* ws = (char*)d_ws;
    unsigned short* hsB     = (unsigned short*)(ws);              // [4096][2048] bf16
    unsigned short* qkvB    = (unsigned short*)(ws + 16777216);   // [4096][6144] bf16
    unsigned short* wqkvT   = (unsigned short*)(ws + 67108864);   // [6144][2048] bf16
    unsigned short* vtB     = (unsigned short*)(ws + 92274688);   // [32][128][2048] bf16
    unsigned short* woT     = (unsigned short*)(ws + 109051904);  // [2048][2048] bf16
    unsigned short* attnout = hsB;   // hsB dead after QKV GEMM

    convert_f32_bf16<<<4096, 256, 0, stream>>>(hs, hsB);
    transpose_w4<<<dim3(64, 64, 4), 256, 0, stream>>>(Wq, Wk, Wv, Wo, wqkvT, woT);

    // QKV fat-wave + fused RoPE epilogue: 256x384 tiles -> 256 blocks = 1 round
    gemm_8phase<6, false, true><<<dim3(256), 512, 0, stream>>>(
        hsB, wqkvT, bq, bk, bv, qkvB, nullptr, 2048, QKN, 16, 8, 4, 1);
    v_transpose<<<dim3(64, 4, 32), 256, 0, stream>>>(qkvB, vtB);
    // attn: 32x32 shape, QBLK=256, 8 waves x 32 q, 256 blocks = 1 round
    attn_kernel<<<dim3(256), 512, 0, stream>>>(qkvB, vtB, attnout);
    // out-proj: 256x128 tiles, 16x16 grid, XCD chunks 4x8, fp32 out
    gemm_8phase<2, true, false><<<dim3(256), 512, 0, stream>>>(
        attnout, woT, nullptr, nullptr, nullptr, nullptr, out, 2048, HID, 16, 4, 8, 0);
}